// Round 9
// baseline (1221.782 us; speedup 1.0000x reference)
//
#include <hip/hip_runtime.h>
#include <math.h>

#define NHE_CONST 20000

typedef float v4f __attribute__((ext_vector_type(4)));

__device__ __forceinline__ float lrelu(float x){ return x >= 0.f ? x : 0.2f * x; }

// ---------------- CSR build (merged) ----------------
__global__ void k_count_all(const int* __restrict__ he_node, const int* __restrict__ he_edge, int inc,
                            const int* __restrict__ dst, int e,
                            int* cntN, int* cntHE, int* cntD){
  int i = blockIdx.x * blockDim.x + threadIdx.x;
  if (i < inc){ atomicAdd(&cntN[he_node[i]], 1); atomicAdd(&cntHE[he_edge[i]], 1); }
  if (i < e) atomicAdd(&cntD[dst[i]], 1);
}

__global__ __launch_bounds__(256) void k_scan_sums3(
    const int* __restrict__ p0, int n0, int* __restrict__ b0,
    const int* __restrict__ p1, int n1, int* __restrict__ b1,
    const int* __restrict__ p2, int n2, int* __restrict__ b2){
  const int* p; int n; int* bs;
  if (blockIdx.y == 0){ p = p0; n = n0; bs = b0; }
  else if (blockIdx.y == 1){ p = p1; n = n1; bs = b1; }
  else { p = p2; n = n2; bs = b2; }
  int nb = (n + 1023) / 1024;
  if ((int)blockIdx.x >= nb) return;
  __shared__ int sm[256];
  int base = blockIdx.x * 1024;
  int v = 0;
  for (int i = threadIdx.x; i < 1024; i += 256){
    int idx = base + i;
    v += (idx < n) ? p[idx] : 0;
  }
  sm[threadIdx.x] = v; __syncthreads();
  for (int d = 128; d > 0; d >>= 1){
    if (threadIdx.x < d) sm[threadIdx.x] += sm[threadIdx.x + d];
    __syncthreads();
  }
  if (threadIdx.x == 0) bs[blockIdx.x] = sm[0];
}

__global__ void k_scan_bsum3(int* b0, int nb0, int* b1, int nb1, int* b2, int nb2){
  int t = threadIdx.x;
  int* bs; int nb;
  if (t == 0){ bs = b0; nb = nb0; }
  else if (t == 1){ bs = b1; nb = nb1; }
  else if (t == 2){ bs = b2; nb = nb2; }
  else return;
  int acc = 0;
  for (int i = 0; i < nb; i++){ int v = bs[i]; bs[i] = acc; acc += v; }
}

__global__ __launch_bounds__(256) void k_scan_apply3(
    const int* __restrict__ c0, int n0, const int* __restrict__ s0, int* __restrict__ o0, int* __restrict__ u0,
    const int* __restrict__ c1, int n1, const int* __restrict__ s1, int* __restrict__ o1, int* __restrict__ u1,
    const int* __restrict__ c2, int n2, const int* __restrict__ s2, int* __restrict__ o2, int* __restrict__ u2){
  const int* cnt; int n; const int* bsum; int* off; int* cur;
  if (blockIdx.y == 0){ cnt = c0; n = n0; bsum = s0; off = o0; cur = u0; }
  else if (blockIdx.y == 1){ cnt = c1; n = n1; bsum = s1; off = o1; cur = u1; }
  else { cnt = c2; n = n2; bsum = s2; off = o2; cur = u2; }
  int nb = (n + 1023) / 1024;
  int b = blockIdx.x;
  if (b >= nb) return;
  __shared__ int sm[256];
  int base = b * 1024 + threadIdx.x * 4;
  int v[4];
  #pragma unroll
  for (int i = 0; i < 4; i++) v[i] = (base + i < n) ? cnt[base + i] : 0;
  int s = v[0] + v[1] + v[2] + v[3];
  sm[threadIdx.x] = s; __syncthreads();
  int x = s;
  for (int d = 1; d < 256; d <<= 1){
    int t = (threadIdx.x >= d) ? sm[threadIdx.x - d] : 0;
    __syncthreads();
    x += t; sm[threadIdx.x] = x;
    __syncthreads();
  }
  int run = x - s + bsum[b];
  #pragma unroll
  for (int i = 0; i < 4; i++){
    if (base + i < n) cur[base + i] = run;
    run += v[i];
    if (base + i < n) off[base + i + 1] = run;
  }
  if (b == 0 && threadIdx.x == 0) off[0] = 0;
}

// Sliced fill: key-range slices pin scatter regions to one XCD's L2 (kills write amp).
__global__ __launch_bounds__(256) void k_fill_sliced(
    const int* __restrict__ he_node, const int* __restrict__ he_edge, int inc,
    const int* __restrict__ src, const int* __restrict__ dst, int e,
    int* curN, int* curHE, int* curD,
    int* __restrict__ nHEs, int* __restrict__ heNodes, int* __restrict__ srcIdx,
    int nN, int nHE){
  int slice = blockIdx.x & 7;
  int group = blockIdx.x >> 3;
  int ngroups = gridDim.x >> 3;
  int sN  = (nN  + 7) >> 3;  int loN  = slice * sN;  int hiN  = min(loN + sN, nN);
  int sHE = (nHE + 7) >> 3;  int loHE = slice * sHE; int hiHE = min(loHE + sHE, nHE);
  int stride = ngroups * 256;
  int start = group * 256 + threadIdx.x;
  for (int i = start; i < e; i += stride){
    int d = dst[i];
    if (d >= loN && d < hiN){
      int p = atomicAdd(&curD[d], 1);
      srcIdx[p] = src[i];
    }
  }
  for (int i = start; i < inc; i += stride){
    int nd = he_node[i], he = he_edge[i];
    if (nd >= loN && nd < hiN){
      int q = atomicAdd(&curN[nd], 1);
      nHEs[q] = he;
    }
    if (he >= loHE && he < hiHE){
      int p = atomicAdd(&curHE[he], 1);
      heNodes[p] = nd;
    }
  }
}

// ---------------- fp32 GEMM 128x128 + bias+relu, prefetch + forced 4 waves/EU ----------------
__global__ __launch_bounds__(256, 4) void k_gemm128_bias_relu(
    const float* __restrict__ A, const float* __restrict__ B, float* __restrict__ C,
    int M, int N, int K, const float* __restrict__ bias){
  __shared__ float As[16][132];
  __shared__ float Bs[16][128];
  int tid = threadIdx.x;
  int tn = tid & 15, tm = tid >> 4;
  int bm = blockIdx.x * 128, bn = blockIdx.y * 128;

  float acc[8][8];
  #pragma unroll
  for (int i = 0; i < 8; i++)
    #pragma unroll
    for (int j = 0; j < 8; j++) acc[i][j] = 0.f;

  int arow = tid >> 2, akc = (tid & 3) * 4;
  int brow = tid >> 4, bcol = (tid & 15) * 8;
  int gr0 = bm + arow, gr1 = bm + arow + 64;

  float4 pa0, pa1, pb0, pb1;
  {
    pa0 = (gr0 < M) ? *(const float4*)(A + (size_t)gr0 * K + akc) : make_float4(0,0,0,0);
    pa1 = (gr1 < M) ? *(const float4*)(A + (size_t)gr1 * K + akc) : make_float4(0,0,0,0);
    const float* bp = B + (size_t)brow * N + bn + bcol;
    pb0 = *(const float4*)bp; pb1 = *(const float4*)(bp + 4);
  }

  for (int k0 = 0; k0 < K; k0 += 16){
    As[akc + 0][arow] = pa0.x; As[akc + 1][arow] = pa0.y;
    As[akc + 2][arow] = pa0.z; As[akc + 3][arow] = pa0.w;
    As[akc + 0][arow + 64] = pa1.x; As[akc + 1][arow + 64] = pa1.y;
    As[akc + 2][arow + 64] = pa1.z; As[akc + 3][arow + 64] = pa1.w;
    *(float4*)&Bs[brow][bcol]     = pb0;
    *(float4*)&Bs[brow][bcol + 4] = pb1;
    __syncthreads();

    int k1 = k0 + 16;
    if (k1 < K){
      pa0 = (gr0 < M) ? *(const float4*)(A + (size_t)gr0 * K + k1 + akc) : make_float4(0,0,0,0);
      pa1 = (gr1 < M) ? *(const float4*)(A + (size_t)gr1 * K + k1 + akc) : make_float4(0,0,0,0);
      const float* bp = B + (size_t)(k1 + brow) * N + bn + bcol;
      pb0 = *(const float4*)bp; pb1 = *(const float4*)(bp + 4);
    }

    #pragma unroll
    for (int k = 0; k < 16; k++){
      float4 a0 = *(const float4*)&As[k][tm * 8];
      float4 a1 = *(const float4*)&As[k][tm * 8 + 4];
      float4 b0 = *(const float4*)&Bs[k][tn * 8];
      float4 b1 = *(const float4*)&Bs[k][tn * 8 + 4];
      float a[8] = {a0.x, a0.y, a0.z, a0.w, a1.x, a1.y, a1.z, a1.w};
      float bb[8] = {b0.x, b0.y, b0.z, b0.w, b1.x, b1.y, b1.z, b1.w};
      #pragma unroll
      for (int i = 0; i < 8; i++)
        #pragma unroll
        for (int j = 0; j < 8; j++) acc[i][j] += a[i] * bb[j];
    }
    __syncthreads();
  }
  const float* bvp = bias + bn + tn * 8;
  float4 bb0 = *(const float4*)bvp;
  float4 bb1 = *(const float4*)(bvp + 4);
  float bv[8] = {bb0.x, bb0.y, bb0.z, bb0.w, bb1.x, bb1.y, bb1.z, bb1.w};
  #pragma unroll
  for (int i = 0; i < 8; i++){
    int r = bm + tm * 8 + i;
    if (r < M){
      float* cp = C + (size_t)r * N + bn + tn * 8;
      *(float4*)cp       = make_float4(fmaxf(acc[i][0]+bv[0],0.f), fmaxf(acc[i][1]+bv[1],0.f),
                                       fmaxf(acc[i][2]+bv[2],0.f), fmaxf(acc[i][3]+bv[3],0.f));
      *(float4*)(cp + 4) = make_float4(fmaxf(acc[i][4]+bv[4],0.f), fmaxf(acc[i][5]+bv[5],0.f),
                                       fmaxf(acc[i][6]+bv[6],0.f), fmaxf(acc[i][7]+bv[7],0.f));
    }
  }
}

// ---------------- fp32 GEMM 128x128 + fused row-dots, prefetch + forced 4 waves/EU ----------------
__global__ __launch_bounds__(256, 4) void k_gemm128_dots(
    const float* __restrict__ A, const float* __restrict__ B, float* __restrict__ C,
    int M, int N, int K, const float* __restrict__ a_s, const float* __restrict__ a_d,
    float* __restrict__ vs, float* __restrict__ vd){
  __shared__ float As[16][132];
  __shared__ float Bs[16][128];
  int tid = threadIdx.x;
  int tn = tid & 15, tm = tid >> 4;
  int bm = blockIdx.x * 128, bn = blockIdx.y * 128;

  float acc[8][8];
  #pragma unroll
  for (int i = 0; i < 8; i++)
    #pragma unroll
    for (int j = 0; j < 8; j++) acc[i][j] = 0.f;

  int arow = tid >> 2, akc = (tid & 3) * 4;
  int brow = tid >> 4, bcol = (tid & 15) * 8;
  int gr0 = bm + arow, gr1 = bm + arow + 64;

  float4 pa0, pa1, pb0, pb1;
  {
    pa0 = (gr0 < M) ? *(const float4*)(A + (size_t)gr0 * K + akc) : make_float4(0,0,0,0);
    pa1 = (gr1 < M) ? *(const float4*)(A + (size_t)gr1 * K + akc) : make_float4(0,0,0,0);
    const float* bp = B + (size_t)brow * N + bn + bcol;
    pb0 = *(const float4*)bp; pb1 = *(const float4*)(bp + 4);
  }

  for (int k0 = 0; k0 < K; k0 += 16){
    As[akc + 0][arow] = pa0.x; As[akc + 1][arow] = pa0.y;
    As[akc + 2][arow] = pa0.z; As[akc + 3][arow] = pa0.w;
    As[akc + 0][arow + 64] = pa1.x; As[akc + 1][arow + 64] = pa1.y;
    As[akc + 2][arow + 64] = pa1.z; As[akc + 3][arow + 64] = pa1.w;
    *(float4*)&Bs[brow][bcol]     = pb0;
    *(float4*)&Bs[brow][bcol + 4] = pb1;
    __syncthreads();

    int k1 = k0 + 16;
    if (k1 < K){
      pa0 = (gr0 < M) ? *(const float4*)(A + (size_t)gr0 * K + k1 + akc) : make_float4(0,0,0,0);
      pa1 = (gr1 < M) ? *(const float4*)(A + (size_t)gr1 * K + k1 + akc) : make_float4(0,0,0,0);
      const float* bp = B + (size_t)(k1 + brow) * N + bn + bcol;
      pb0 = *(const float4*)bp; pb1 = *(const float4*)(bp + 4);
    }

    #pragma unroll
    for (int k = 0; k < 16; k++){
      float4 a0 = *(const float4*)&As[k][tm * 8];
      float4 a1 = *(const float4*)&As[k][tm * 8 + 4];
      float4 b0 = *(const float4*)&Bs[k][tn * 8];
      float4 b1 = *(const float4*)&Bs[k][tn * 8 + 4];
      float a[8] = {a0.x, a0.y, a0.z, a0.w, a1.x, a1.y, a1.z, a1.w};
      float bb[8] = {b0.x, b0.y, b0.z, b0.w, b1.x, b1.y, b1.z, b1.w};
      #pragma unroll
      for (int i = 0; i < 8; i++)
        #pragma unroll
        for (int j = 0; j < 8; j++) acc[i][j] += a[i] * bb[j];
    }
    __syncthreads();
  }
  // C store
  #pragma unroll
  for (int i = 0; i < 8; i++){
    int r = bm + tm * 8 + i;
    if (r < M){
      float* cp = C + (size_t)r * N + bn + tn * 8;
      *(float4*)cp       = make_float4(acc[i][0], acc[i][1], acc[i][2], acc[i][3]);
      *(float4*)(cp + 4) = make_float4(acc[i][4], acc[i][5], acc[i][6], acc[i][7]);
    }
  }
  // fused row dots (partial over this bn tile)
  const float* asp = a_s + bn + tn * 8;
  const float* adp = a_d + bn + tn * 8;
  float4 s0 = *(const float4*)asp, s1 = *(const float4*)(asp + 4);
  float4 d0 = *(const float4*)adp, d1 = *(const float4*)(adp + 4);
  float sv[8] = {s0.x, s0.y, s0.z, s0.w, s1.x, s1.y, s1.z, s1.w};
  float dv[8] = {d0.x, d0.y, d0.z, d0.w, d1.x, d1.y, d1.z, d1.w};
  #pragma unroll
  for (int i = 0; i < 8; i++){
    float ps = 0.f, pd = 0.f;
    #pragma unroll
    for (int j = 0; j < 8; j++){ ps = fmaf(acc[i][j], sv[j], ps); pd = fmaf(acc[i][j], dv[j], pd); }
    ps += __shfl_xor(ps, 1); ps += __shfl_xor(ps, 2); ps += __shfl_xor(ps, 4); ps += __shfl_xor(ps, 8);
    pd += __shfl_xor(pd, 1); pd += __shfl_xor(pd, 2); pd += __shfl_xor(pd, 4); pd += __shfl_xor(pd, 8);
    int r = bm + tm * 8 + i;
    if (tn == 0 && r < M){ atomicAdd(&vs[r], ps); atomicAdd(&vd[r], pd); }
  }
}

// ---------------- fp32 GEMM 64x64 + fused full row-dots (stage 3), BM=64, pipelined ----------------
__global__ __launch_bounds__(256) void k_gemm64_dots(
    const float* __restrict__ A, const float* __restrict__ B, float* __restrict__ C,
    int M, int N, int K, const float* __restrict__ a_s, const float* __restrict__ a_d,
    float* __restrict__ vs, float* __restrict__ vd){
  __shared__ float As[16][68];
  __shared__ float Bs[16][64];
  int tid = threadIdx.x;
  int tn = tid & 15, tm = tid >> 4;
  int bm = blockIdx.x * 64;

  float acc[4][4];
  #pragma unroll
  for (int i = 0; i < 4; i++)
    #pragma unroll
    for (int j = 0; j < 4; j++) acc[i][j] = 0.f;

  int arow = tid >> 2, akc = (tid & 3) * 4;
  int brow = tid >> 4, bcol = (tid & 15) * 4;
  int gr = bm + arow;

  float4 pa, pb;
  pa = (gr < M) ? *(const float4*)(A + (size_t)gr * K + akc) : make_float4(0,0,0,0);
  pb = *(const float4*)(B + (size_t)brow * N + bcol);

  for (int k0 = 0; k0 < K; k0 += 16){
    As[akc + 0][arow] = pa.x; As[akc + 1][arow] = pa.y;
    As[akc + 2][arow] = pa.z; As[akc + 3][arow] = pa.w;
    *(float4*)&Bs[brow][bcol] = pb;
    __syncthreads();

    int k1 = k0 + 16;
    if (k1 < K){
      pa = (gr < M) ? *(const float4*)(A + (size_t)gr * K + k1 + akc) : make_float4(0,0,0,0);
      pb = *(const float4*)(B + (size_t)(k1 + brow) * N + bcol);
    }

    #pragma unroll
    for (int k = 0; k < 16; k++){
      float4 a = *(const float4*)&As[k][tm * 4];
      float4 b = *(const float4*)&Bs[k][tn * 4];
      float av[4] = {a.x, a.y, a.z, a.w};
      float bb[4] = {b.x, b.y, b.z, b.w};
      #pragma unroll
      for (int i = 0; i < 4; i++)
        #pragma unroll
        for (int j = 0; j < 4; j++) acc[i][j] += av[i] * bb[j];
    }
    __syncthreads();
  }
  float4 s = *(const float4*)(a_s + tn * 4);
  float4 d = *(const float4*)(a_d + tn * 4);
  #pragma unroll
  for (int i = 0; i < 4; i++){
    int r = bm + tm * 4 + i;
    if (r < M)
      *(float4*)(C + (size_t)r * N + tn * 4) = make_float4(acc[i][0], acc[i][1], acc[i][2], acc[i][3]);
    float ps = acc[i][0]*s.x + acc[i][1]*s.y + acc[i][2]*s.z + acc[i][3]*s.w;
    float pd = acc[i][0]*d.x + acc[i][1]*d.y + acc[i][2]*d.z + acc[i][3]*d.w;
    ps += __shfl_xor(ps, 1); ps += __shfl_xor(ps, 2); ps += __shfl_xor(ps, 4); ps += __shfl_xor(ps, 8);
    pd += __shfl_xor(pd, 1); pd += __shfl_xor(pd, 2); pd += __shfl_xor(pd, 4); pd += __shfl_xor(pd, 8);
    if (tn == 0 && r < M){ vs[r] = ps; vd[r] = pd; }
  }
}

// ---------------- hypergraph aggregation in 128-dim input space ----------------
__global__ __launch_bounds__(256) void k_hg_edge128(const float* __restrict__ x, const int* __restrict__ off,
                                                    const int* __restrict__ heNodes, float* __restrict__ mout,
                                                    int nhe){
  int wid = (blockIdx.x * blockDim.x + threadIdx.x) >> 6;
  int lane = threadIdx.x & 63;
  if (wid >= nhe) return;
  int s = off[wid], e = off[wid + 1];
  float2 a0 = make_float2(0,0), a1 = a0, a2 = a0, a3 = a0;
  int i = s;
  for (; i + 8 <= e; i += 8){
    int n8[8];
    #pragma unroll
    for (int u = 0; u < 8; u++) n8[u] = heNodes[i + u];
    float2 v8[8];
    #pragma unroll
    for (int u = 0; u < 8; u++) v8[u] = *(const float2*)(x + (size_t)n8[u] * 128 + lane * 2);
    #pragma unroll
    for (int u = 0; u < 8; u++){
      float2* c = (u & 3) == 0 ? &a0 : (u & 3) == 1 ? &a1 : (u & 3) == 2 ? &a2 : &a3;
      c->x += v8[u].x; c->y += v8[u].y;
    }
  }
  for (; i < e; i++){
    int nd = heNodes[i];
    float2 v = *(const float2*)(x + (size_t)nd * 128 + lane * 2);
    a0.x += v.x; a0.y += v.y;
  }
  float inv = (e > s) ? 1.f / (float)(e - s) : 0.f;
  float2 o = make_float2((a0.x + a1.x + a2.x + a3.x) * inv, (a0.y + a1.y + a2.y + a3.y) * inv);
  *(float2*)(mout + (size_t)wid * 128 + lane * 2) = o;
}

__global__ __launch_bounds__(256) void k_hg_node128(const float* __restrict__ m_in, const int* __restrict__ off,
                                                    const int* __restrict__ nHEs, float* __restrict__ out,
                                                    int nn){
  int wid = (blockIdx.x * blockDim.x + threadIdx.x) >> 6;
  int lane = threadIdx.x & 63;
  if (wid >= nn) return;
  int s = off[wid], e = off[wid + 1];
  float2 a0 = make_float2(0,0), a1 = a0, a2 = a0, a3 = a0;
  int i = s;
  for (; i + 4 <= e; i += 4){
    int n0 = nHEs[i], n1 = nHEs[i+1], n2 = nHEs[i+2], n3 = nHEs[i+3];
    float2 v0 = *(const float2*)(m_in + (size_t)n0 * 128 + lane * 2);
    float2 v1 = *(const float2*)(m_in + (size_t)n1 * 128 + lane * 2);
    float2 v2 = *(const float2*)(m_in + (size_t)n2 * 128 + lane * 2);
    float2 v3 = *(const float2*)(m_in + (size_t)n3 * 128 + lane * 2);
    a0.x += v0.x; a0.y += v0.y; a1.x += v1.x; a1.y += v1.y;
    a2.x += v2.x; a2.y += v2.y; a3.x += v3.x; a3.y += v3.y;
  }
  for (; i < e; i++){
    int he = nHEs[i];
    float2 v = *(const float2*)(m_in + (size_t)he * 128 + lane * 2);
    a0.x += v.x; a0.y += v.y;
  }
  float inv = (e > s) ? 1.f / (float)(e - s) : 0.f;
  float2 o = make_float2((a0.x + a1.x + a2.x + a3.x) * inv, (a0.y + a1.y + a2.y + a3.y) * inv);
  *(float2*)(out + (size_t)wid * 128 + lane * 2) = o;
}

// ---------------- GAT aggregation, fused softmax, no max pass, 8x unroll ----------------
__global__ __launch_bounds__(256) void k_gat256(const float* __restrict__ h, const float* __restrict__ asr,
                                                const float* __restrict__ ads, const int* __restrict__ off,
                                                const int* __restrict__ srcIdx, const float* __restrict__ bias,
                                                float* __restrict__ out, int nn){
  int wid = (blockIdx.x * blockDim.x + threadIdx.x) >> 6;
  int lane = threadIdx.x & 63;
  if (wid >= nn) return;
  float ad = ads[wid];
  int s = off[wid], e = off[wid + 1];

  float ssum = 0.f;
  float4 c0 = make_float4(0,0,0,0), c1 = c0, c2 = c0, c3 = c0;
  {
    float e0 = __expf(lrelu(asr[wid] + ad));   // self-loop
    ssum += e0;
    float4 v = *(const float4*)(h + (size_t)wid * 256 + lane * 4);
    c0.x += e0 * v.x; c0.y += e0 * v.y; c0.z += e0 * v.z; c0.w += e0 * v.w;
  }
  int i = s;
  for (; i + 8 <= e; i += 8){
    int n8[8];
    #pragma unroll
    for (int u = 0; u < 8; u++) n8[u] = srcIdx[i + u];
    float f8[8];
    #pragma unroll
    for (int u = 0; u < 8; u++) f8[u] = asr[n8[u]];
    float4 v8[8];
    #pragma unroll
    for (int u = 0; u < 8; u++) v8[u] = *(const float4*)(h + (size_t)n8[u] * 256 + lane * 4);
    #pragma unroll
    for (int u = 0; u < 8; u++){
      float ee = __expf(lrelu(f8[u] + ad));
      ssum += ee;
      float4* c = (u & 3) == 0 ? &c0 : (u & 3) == 1 ? &c1 : (u & 3) == 2 ? &c2 : &c3;
      c->x += ee * v8[u].x; c->y += ee * v8[u].y; c->z += ee * v8[u].z; c->w += ee * v8[u].w;
    }
  }
  for (; i < e; i++){
    int sn = srcIdx[i];
    float ee = __expf(lrelu(asr[sn] + ad));
    ssum += ee;
    float4 v = *(const float4*)(h + (size_t)sn * 256 + lane * 4);
    c0.x += ee * v.x; c0.y += ee * v.y; c0.z += ee * v.z; c0.w += ee * v.w;
  }
  float r = 1.f / (ssum + 1e-16f);
  float4 b = *(const float4*)(bias + lane * 4);
  v4f o;
  o.x = fmaxf((c0.x + c1.x + c2.x + c3.x) * r + b.x, 0.f);
  o.y = fmaxf((c0.y + c1.y + c2.y + c3.y) * r + b.y, 0.f);
  o.z = fmaxf((c0.z + c1.z + c2.z + c3.z) * r + b.z, 0.f);
  o.w = fmaxf((c0.w + c1.w + c2.w + c3.w) * r + b.w, 0.f);
  __builtin_nontemporal_store(o, (v4f*)(out + (size_t)wid * 256 + lane * 4));
}

__global__ __launch_bounds__(256) void k_gat64(const float* __restrict__ h, const float* __restrict__ asr,
                                               const float* __restrict__ ads, const int* __restrict__ off,
                                               const int* __restrict__ srcIdx, const float* __restrict__ bias,
                                               float* __restrict__ out, int nn){
  int wid = (blockIdx.x * blockDim.x + threadIdx.x) >> 6;
  int lane = threadIdx.x & 63;
  if (wid >= nn) return;
  float ad = ads[wid];
  int s = off[wid], e = off[wid + 1];

  float ssum = 0.f;
  float c0 = 0.f, c1 = 0.f, c2 = 0.f, c3 = 0.f;
  {
    float e0 = __expf(lrelu(asr[wid] + ad));
    ssum += e0;
    c0 += e0 * h[(size_t)wid * 64 + lane];
  }
  int i = s;
  for (; i + 8 <= e; i += 8){
    int n8[8];
    #pragma unroll
    for (int u = 0; u < 8; u++) n8[u] = srcIdx[i + u];
    float f8[8], v8[8];
    #pragma unroll
    for (int u = 0; u < 8; u++) f8[u] = asr[n8[u]];
    #pragma unroll
    for (int u = 0; u < 8; u++) v8[u] = h[(size_t)n8[u] * 64 + lane];
    #pragma unroll
    for (int u = 0; u < 8; u++){
      float ee = __expf(lrelu(f8[u] + ad));
      ssum += ee;
      if ((u & 3) == 0) c0 += ee * v8[u];
      else if ((u & 3) == 1) c1 += ee * v8[u];
      else if ((u & 3) == 2) c2 += ee * v8[u];
      else c3 += ee * v8[u];
    }
  }
  for (; i < e; i++){
    int sn = srcIdx[i];
    float ee = __expf(lrelu(asr[sn] + ad));
    ssum += ee;
    c0 += ee * h[(size_t)sn * 64 + lane];
  }
  float r = 1.f / (ssum + 1e-16f);
  out[(size_t)wid * 64 + lane] = fmaxf((c0 + c1 + c2 + c3) * r + bias[lane], 0.f);
}

// ---------------- decode: GEMM-tiled MLP, 128 edges/block ----------------
#define DEC_EPB 128

__device__ __forceinline__ void dec_stageW(float (*Ws)[68], const float* __restrict__ W, int tid){
  #pragma unroll
  for (int i = 0; i < 4; i++){
    int idx = tid + i * 256;
    int r = idx >> 4, c = (idx & 15) * 4;
    *(float4*)&Ws[r][c] = *(const float4*)(W + r * 64 + c);
  }
}

__device__ __forceinline__ void dec_gather(float (*act)[132], const float* __restrict__ z,
                                           const int* __restrict__ idxv, int ebase, int wv, int lane, int L){
  #pragma unroll 4
  for (int t = 0; t < 32; t++){
    int le = wv * 32 + t;
    int e = ebase + le;
    int nd = (e < L) ? idxv[e] : 0;
    act[lane][le] = z[(size_t)nd * 64 + lane];
  }
}

__device__ __forceinline__ void dec_mac64(const float (*act)[132], const float (*Ws)[68],
                                          int tm, int tn, float (&acc)[8][4]){
  #pragma unroll 8
  for (int k = 0; k < 64; k++){
    float4 a0 = *(const float4*)&act[k][tm * 8];
    float4 a1 = *(const float4*)&act[k][tm * 8 + 4];
    float4 b  = *(const float4*)&Ws[k][tn * 4];
    float a[8] = {a0.x, a0.y, a0.z, a0.w, a1.x, a1.y, a1.z, a1.w};
    #pragma unroll
    for (int i = 0; i < 8; i++){
      acc[i][0] = fmaf(a[i], b.x, acc[i][0]);
      acc[i][1] = fmaf(a[i], b.y, acc[i][1]);
      acc[i][2] = fmaf(a[i], b.z, acc[i][2]);
      acc[i][3] = fmaf(a[i], b.w, acc[i][3]);
    }
  }
}

__device__ __forceinline__ void dec_writeback(float (*act)[132], int tm, int tn, const float (&acc)[8][4]){
  #pragma unroll
  for (int j = 0; j < 4; j++)
    #pragma unroll
    for (int i = 0; i < 8; i++)
      act[tn * 4 + j][tm * 8 + i] = fmaxf(acc[i][j], 0.f);
}

__global__ __launch_bounds__(256) void k_decode(const float* __restrict__ z, const int* __restrict__ eli, int L,
    const float* __restrict__ Wm1, const float* __restrict__ bm1,
    const float* __restrict__ Wm2, const float* __restrict__ bm2,
    const float* __restrict__ Wm3, const float* __restrict__ bm3,
    const float* __restrict__ Wm4, const float* __restrict__ bm4,
    float* __restrict__ outPred, float* __restrict__ outProb, float* __restrict__ outLog){
  __shared__ float act[64][132];
  __shared__ float Ws[64][68];
  __shared__ float W4s[192];
  __shared__ float b1s[64], b2s[64], b3s[64], b4s[4];

  int tid = threadIdx.x, lane = tid & 63, wv = tid >> 6;
  int tm = tid >> 4, tn = tid & 15;
  int ebase = blockIdx.x * DEC_EPB;

  if (tid < 64){ b1s[tid] = bm1[tid]; b2s[tid] = bm2[tid]; b3s[tid] = bm3[tid]; }
  if (tid < 3) b4s[tid] = bm4[tid];
  if (tid < 192) W4s[tid] = Wm4[tid];

  dec_stageW(Ws, Wm1, tid);
  dec_gather(act, z, eli, ebase, wv, lane, L);
  __syncthreads();

  float acc[8][4];
  {
    float bx = b1s[tn*4], by = b1s[tn*4+1], bz = b1s[tn*4+2], bw = b1s[tn*4+3];
    #pragma unroll
    for (int i = 0; i < 8; i++){ acc[i][0]=bx; acc[i][1]=by; acc[i][2]=bz; acc[i][3]=bw; }
  }
  dec_mac64(act, Ws, tm, tn, acc);
  __syncthreads();

  dec_stageW(Ws, Wm1 + 4096, tid);
  dec_gather(act, z, eli + L, ebase, wv, lane, L);
  __syncthreads();
  dec_mac64(act, Ws, tm, tn, acc);
  __syncthreads();

  dec_writeback(act, tm, tn, acc);
  dec_stageW(Ws, Wm2, tid);
  __syncthreads();

  {
    float bx = b2s[tn*4], by = b2s[tn*4+1], bz = b2s[tn*4+2], bw = b2s[tn*4+3];
    #pragma unroll
    for (int i = 0; i < 8; i++){ acc[i][0]=bx; acc[i][1]=by; acc[i][2]=bz; acc[i][3]=bw; }
  }
  dec_mac64(act, Ws, tm, tn, acc);
  __syncthreads();
  dec_writeback(act, tm, tn, acc);
  dec_stageW(Ws, Wm3, tid);
  __syncthreads();

  {
    float bx = b3s[tn*4], by = b3s[tn*4+1], bz = b3s[tn*4+2], bw = b3s[tn*4+3];
    #pragma unroll
    for (int i = 0; i < 8; i++){ acc[i][0]=bx; acc[i][1]=by; acc[i][2]=bz; acc[i][3]=bw; }
  }
  dec_mac64(act, Ws, tm, tn, acc);
  __syncthreads();
  dec_writeback(act, tm, tn, acc);
  __syncthreads();

  if (tid < DEC_EPB){
    int e = tid;
    float o0 = b4s[0], o1 = b4s[1], o2 = b4s[2];
    #pragma unroll 8
    for (int k = 0; k < 64; k++){
      float av = act[k][e];
      o0 = fmaf(av, W4s[k*3+0], o0);
      o1 = fmaf(av, W4s[k*3+1], o1);
      o2 = fmaf(av, W4s[k*3+2], o2);
    }
    int eg = ebase + e;
    if (eg < L){
      int am = 0; float best = o0;
      if (o1 > best){ am = 1; best = o1; }
      if (o2 > best){ am = 2; best = o2; }
      outPred[eg] = (float)am;
      outProb[eg] = best;
      outLog[(size_t)eg * 3 + 0] = o0;
      outLog[(size_t)eg * 3 + 1] = o1;
      outLog[(size_t)eg * 3 + 2] = o2;
    }
  }
}

// ---------------- launch ----------------
extern "C" void kernel_launch(void* const* d_in, const int* in_sizes, int n_in,
                              void* d_out, int out_size, void* d_ws, size_t ws_size,
                              hipStream_t stream){
  const float* x      = (const float*)d_in[0];
  const int*   ei     = (const int*)d_in[1];
  const int*   he_node= (const int*)d_in[2];
  const int*   he_edge= (const int*)d_in[3];
  const int*   eli    = (const int*)d_in[4];
  const float* W1  = (const float*)d_in[5];
  const float* b1  = (const float*)d_in[6];
  const float* W2  = (const float*)d_in[7];
  const float* a2s = (const float*)d_in[8];
  const float* a2d = (const float*)d_in[9];
  const float* b2  = (const float*)d_in[10];
  const float* W3  = (const float*)d_in[11];
  const float* a3s = (const float*)d_in[12];
  const float* a3d = (const float*)d_in[13];
  const float* b3  = (const float*)d_in[14];
  const float* Wm1 = (const float*)d_in[15]; const float* bm1 = (const float*)d_in[16];
  const float* Wm2 = (const float*)d_in[17]; const float* bm2 = (const float*)d_in[18];
  const float* Wm3 = (const float*)d_in[19]; const float* bm3 = (const float*)d_in[20];
  const float* Wm4 = (const float*)d_in[21]; const float* bm4 = (const float*)d_in[22];

  const int N   = in_sizes[0] / 128;   // 50000
  const int E   = in_sizes[1] / 2;     // 800000
  const int INC = in_sizes[2];         // 400000
  const int NHE = NHE_CONST;           // 20000
  const int L   = in_sizes[4] / 2;     // 100000

  char* wbase = (char*)d_ws;
  size_t woff = 0;
  auto walloc = [&](size_t bytes) -> void* {
    void* p = wbase + woff;
    woff = (woff + bytes + 255) & ~(size_t)255;
    return p;
  };
  float* pre1   = (float*)walloc((size_t)N * 128 * 4);
  float* mbuf   = (float*)walloc((size_t)NHE * 128 * 4);
  float* h1     = (float*)walloc((size_t)N * 256 * 4);   // also reused as h2
  float* t2     = (float*)walloc((size_t)N * 256 * 4);
  float* t3     = (float*)walloc((size_t)N * 64 * 4);
  float* zbuf   = (float*)walloc((size_t)N * 64 * 4);
  float* vboth  = (float*)walloc((size_t)2 * N * 4);
  int* heOff  = (int*)walloc((size_t)(NHE + 1) * 4);
  int* nOff   = (int*)walloc((size_t)(N + 1) * 4);
  int* dOff   = (int*)walloc((size_t)(N + 1) * 4);
  int* cntAll = (int*)walloc((size_t)(NHE + 2 * N) * 4);
  int* curAll = (int*)walloc((size_t)(NHE + 2 * N) * 4);
  int* heNodes= (int*)walloc((size_t)INC * 4);
  int* nHEs   = (int*)walloc((size_t)INC * 4);
  int* srcIdx = (int*)walloc((size_t)E * 4);
  int* bsumA  = (int*)walloc(64 * 4);
  int* bsumB  = (int*)walloc(64 * 4);
  int* bsumC  = (int*)walloc(64 * 4);

  int* cntHE = cntAll;           int* cntN = cntAll + NHE; int* cntD = cntAll + NHE + N;
  int* curHE = curAll;           int* curN = curAll + NHE; int* curD = curAll + NHE + N;
  float* vsrc = vboth;           float* vdst = vboth + N;
  float* h2 = h1;                // h1 dead after stage-2 GEMM reads it

  const int* srcPtr = ei;
  const int* dstPtr = ei + E;

  // --- CSR build ---
  hipMemsetAsync(cntAll, 0, (size_t)(NHE + 2 * N) * 4, stream);
  hipMemsetAsync(vboth,  0, (size_t)2 * N * 4, stream);
  k_count_all<<<(E + 255) / 256, 256, 0, stream>>>(he_node, he_edge, INC, dstPtr, E, cntN, cntHE, cntD);

  int nbHE = (NHE + 1023) / 1024;
  int nbN  = (N + 1023) / 1024;
  k_scan_sums3<<<dim3(nbN, 3), 256, 0, stream>>>(cntHE, NHE, bsumA, cntN, N, bsumB, cntD, N, bsumC);
  k_scan_bsum3<<<1, 64, 0, stream>>>(bsumA, nbHE, bsumB, nbN, bsumC, nbN);
  k_scan_apply3<<<dim3(nbN, 3), 256, 0, stream>>>(cntHE, NHE, bsumA, heOff, curHE,
                                                  cntN,  N,   bsumB, nOff,  curN,
                                                  cntD,  N,   bsumC, dOff,  curD);
  k_fill_sliced<<<8 * 128, 256, 0, stream>>>(he_node, he_edge, INC, srcPtr, dstPtr, E,
                                             curN, curHE, curD, nHEs, heNodes, srcIdx, N, NHE);

  int gRowA = (N + 127) / 128;
  int gRowB = (N + 63) / 64;
  int gWav  = (N + 3) / 4;

  // --- stage 1: HypergraphConv (aggregate in 128-dim, GEMM last, fused bias+relu) ---
  k_hg_edge128<<<(NHE + 3) / 4, 256, 0, stream>>>(x, heOff, heNodes, mbuf, NHE);
  k_hg_node128<<<gWav, 256, 0, stream>>>(mbuf, nOff, nHEs, pre1, N);
  k_gemm128_bias_relu<<<dim3(gRowA, 2), 256, 0, stream>>>(pre1, W1, h1, N, 256, 128, b1);

  // --- stage 2: GAT 256->256 (dots fused into GEMM) ---
  k_gemm128_dots<<<dim3(gRowA, 2), 256, 0, stream>>>(h1, W2, t2, N, 256, 256, a2s, a2d, vsrc, vdst);
  k_gat256<<<gWav, 256, 0, stream>>>(t2, vsrc, vdst, dOff, srcIdx, b2, h2, N);

  // --- stage 3: GAT 256->64 (dots fused into GEMM) ---
  k_gemm64_dots<<<gRowB, 256, 0, stream>>>(h2, W3, t3, N, 64, 256, a3s, a3d, vsrc, vdst);
  k_gat64<<<gWav, 256, 0, stream>>>(t3, vsrc, vdst, dOff, srcIdx, b3, zbuf, N);

  // --- decode ---
  float* outPred = (float*)d_out;
  float* outProb = outPred + L;
  float* outLog  = outProb + L;
  k_decode<<<(L + DEC_EPB - 1) / DEC_EPB, 256, 0, stream>>>(zbuf, eli, L,
                                    Wm1, bm1, Wm2, bm2, Wm3, bm3, Wm4, bm4,
                                    outPred, outProb, outLog);
}

// Round 10
// 799.849 us; speedup vs baseline: 1.5275x; 1.5275x over previous
//
#include <hip/hip_runtime.h>
#include <math.h>

#define NHE_CONST 20000

typedef float v4f __attribute__((ext_vector_type(4)));

__device__ __forceinline__ float lrelu(float x){ return x >= 0.f ? x : 0.2f * x; }

// ---------------- CSR build (merged) ----------------
__global__ void k_count_all(const int* __restrict__ he_node, const int* __restrict__ he_edge, int inc,
                            const int* __restrict__ dst, int e,
                            int* cntN, int* cntHE, int* cntD){
  int i = blockIdx.x * blockDim.x + threadIdx.x;
  if (i < inc){ atomicAdd(&cntN[he_node[i]], 1); atomicAdd(&cntHE[he_edge[i]], 1); }
  if (i < e) atomicAdd(&cntD[dst[i]], 1);
}

__global__ __launch_bounds__(256) void k_scan_sums3(
    const int* __restrict__ p0, int n0, int* __restrict__ b0,
    const int* __restrict__ p1, int n1, int* __restrict__ b1,
    const int* __restrict__ p2, int n2, int* __restrict__ b2){
  const int* p; int n; int* bs;
  if (blockIdx.y == 0){ p = p0; n = n0; bs = b0; }
  else if (blockIdx.y == 1){ p = p1; n = n1; bs = b1; }
  else { p = p2; n = n2; bs = b2; }
  int nb = (n + 1023) / 1024;
  if ((int)blockIdx.x >= nb) return;
  __shared__ int sm[256];
  int base = blockIdx.x * 1024;
  int v = 0;
  for (int i = threadIdx.x; i < 1024; i += 256){
    int idx = base + i;
    v += (idx < n) ? p[idx] : 0;
  }
  sm[threadIdx.x] = v; __syncthreads();
  for (int d = 128; d > 0; d >>= 1){
    if (threadIdx.x < d) sm[threadIdx.x] += sm[threadIdx.x + d];
    __syncthreads();
  }
  if (threadIdx.x == 0) bs[blockIdx.x] = sm[0];
}

__global__ void k_scan_bsum3(int* b0, int nb0, int* b1, int nb1, int* b2, int nb2){
  int t = threadIdx.x;
  int* bs; int nb;
  if (t == 0){ bs = b0; nb = nb0; }
  else if (t == 1){ bs = b1; nb = nb1; }
  else if (t == 2){ bs = b2; nb = nb2; }
  else return;
  int acc = 0;
  for (int i = 0; i < nb; i++){ int v = bs[i]; bs[i] = acc; acc += v; }
}

__global__ __launch_bounds__(256) void k_scan_apply3(
    const int* __restrict__ c0, int n0, const int* __restrict__ s0, int* __restrict__ o0, int* __restrict__ u0,
    const int* __restrict__ c1, int n1, const int* __restrict__ s1, int* __restrict__ o1, int* __restrict__ u1,
    const int* __restrict__ c2, int n2, const int* __restrict__ s2, int* __restrict__ o2, int* __restrict__ u2){
  const int* cnt; int n; const int* bsum; int* off; int* cur;
  if (blockIdx.y == 0){ cnt = c0; n = n0; bsum = s0; off = o0; cur = u0; }
  else if (blockIdx.y == 1){ cnt = c1; n = n1; bsum = s1; off = o1; cur = u1; }
  else { cnt = c2; n = n2; bsum = s2; off = o2; cur = u2; }
  int nb = (n + 1023) / 1024;
  int b = blockIdx.x;
  if (b >= nb) return;
  __shared__ int sm[256];
  int base = b * 1024 + threadIdx.x * 4;
  int v[4];
  #pragma unroll
  for (int i = 0; i < 4; i++) v[i] = (base + i < n) ? cnt[base + i] : 0;
  int s = v[0] + v[1] + v[2] + v[3];
  sm[threadIdx.x] = s; __syncthreads();
  int x = s;
  for (int d = 1; d < 256; d <<= 1){
    int t = (threadIdx.x >= d) ? sm[threadIdx.x - d] : 0;
    __syncthreads();
    x += t; sm[threadIdx.x] = x;
    __syncthreads();
  }
  int run = x - s + bsum[b];
  #pragma unroll
  for (int i = 0; i < 4; i++){
    if (base + i < n) cur[base + i] = run;
    run += v[i];
    if (base + i < n) off[base + i + 1] = run;
  }
  if (b == 0 && threadIdx.x == 0) off[0] = 0;
}

// Sliced fill: key-range slices pin scatter regions to one XCD's L2 (kills write amp).
__global__ __launch_bounds__(256) void k_fill_sliced(
    const int* __restrict__ he_node, const int* __restrict__ he_edge, int inc,
    const int* __restrict__ src, const int* __restrict__ dst, int e,
    int* curN, int* curHE, int* curD,
    int* __restrict__ nHEs, int* __restrict__ heNodes, int* __restrict__ srcIdx,
    int nN, int nHE){
  int slice = blockIdx.x & 7;
  int group = blockIdx.x >> 3;
  int ngroups = gridDim.x >> 3;
  int sN  = (nN  + 7) >> 3;  int loN  = slice * sN;  int hiN  = min(loN + sN, nN);
  int sHE = (nHE + 7) >> 3;  int loHE = slice * sHE; int hiHE = min(loHE + sHE, nHE);
  int stride = ngroups * 256;
  int start = group * 256 + threadIdx.x;
  for (int i = start; i < e; i += stride){
    int d = dst[i];
    if (d >= loN && d < hiN){
      int p = atomicAdd(&curD[d], 1);
      srcIdx[p] = src[i];
    }
  }
  for (int i = start; i < inc; i += stride){
    int nd = he_node[i], he = he_edge[i];
    if (nd >= loN && nd < hiN){
      int q = atomicAdd(&curN[nd], 1);
      nHEs[q] = he;
    }
    if (he >= loHE && he < hiHE){
      int p = atomicAdd(&curHE[he], 1);
      heNodes[p] = nd;
    }
  }
}

// ---------------- fp32 GEMM 128x128 tile + fused bias+relu (r7 form: no prefetch) ----------------
__global__ __launch_bounds__(256) void k_gemm128_bias_relu(
    const float* __restrict__ A, const float* __restrict__ B, float* __restrict__ C,
    int M, int N, int K, const float* __restrict__ bias){
  __shared__ float As[16][132];
  __shared__ float Bs[16][128];
  int tid = threadIdx.x;
  int tn = tid & 15, tm = tid >> 4;
  int bm = blockIdx.x * 128, bn = blockIdx.y * 128;

  float acc[8][8];
  #pragma unroll
  for (int i = 0; i < 8; i++)
    #pragma unroll
    for (int j = 0; j < 8; j++) acc[i][j] = 0.f;

  int arow = tid >> 2, akc = (tid & 3) * 4;
  int brow = tid >> 4, bcol = (tid & 15) * 8;

  for (int k0 = 0; k0 < K; k0 += 16){
    #pragma unroll
    for (int h = 0; h < 2; h++){
      int r = arow + h * 64;
      int gr = bm + r;
      float4 av = (gr < M) ? *(const float4*)(A + (size_t)gr * K + k0 + akc)
                           : make_float4(0.f, 0.f, 0.f, 0.f);
      As[akc + 0][r] = av.x; As[akc + 1][r] = av.y;
      As[akc + 2][r] = av.z; As[akc + 3][r] = av.w;
    }
    const float* bp = B + (size_t)(k0 + brow) * N + bn + bcol;
    *(float4*)&Bs[brow][bcol]     = *(const float4*)bp;
    *(float4*)&Bs[brow][bcol + 4] = *(const float4*)(bp + 4);
    __syncthreads();

    #pragma unroll
    for (int k = 0; k < 16; k++){
      float4 a0 = *(const float4*)&As[k][tm * 8];
      float4 a1 = *(const float4*)&As[k][tm * 8 + 4];
      float4 b0 = *(const float4*)&Bs[k][tn * 8];
      float4 b1 = *(const float4*)&Bs[k][tn * 8 + 4];
      float a[8] = {a0.x, a0.y, a0.z, a0.w, a1.x, a1.y, a1.z, a1.w};
      float bb[8] = {b0.x, b0.y, b0.z, b0.w, b1.x, b1.y, b1.z, b1.w};
      #pragma unroll
      for (int i = 0; i < 8; i++)
        #pragma unroll
        for (int j = 0; j < 8; j++) acc[i][j] += a[i] * bb[j];
    }
    __syncthreads();
  }
  const float* bvp = bias + bn + tn * 8;
  float4 bb0 = *(const float4*)bvp;
  float4 bb1 = *(const float4*)(bvp + 4);
  float bv[8] = {bb0.x, bb0.y, bb0.z, bb0.w, bb1.x, bb1.y, bb1.z, bb1.w};
  #pragma unroll
  for (int i = 0; i < 8; i++){
    int r = bm + tm * 8 + i;
    if (r < M){
      float* cp = C + (size_t)r * N + bn + tn * 8;
      *(float4*)cp       = make_float4(fmaxf(acc[i][0]+bv[0],0.f), fmaxf(acc[i][1]+bv[1],0.f),
                                       fmaxf(acc[i][2]+bv[2],0.f), fmaxf(acc[i][3]+bv[3],0.f));
      *(float4*)(cp + 4) = make_float4(fmaxf(acc[i][4]+bv[4],0.f), fmaxf(acc[i][5]+bv[5],0.f),
                                       fmaxf(acc[i][6]+bv[6],0.f), fmaxf(acc[i][7]+bv[7],0.f));
    }
  }
}

// ---------------- fp32 GEMM 128x128 + fused row-dots (r7 form: no prefetch) ----------------
__global__ __launch_bounds__(256) void k_gemm128_dots(
    const float* __restrict__ A, const float* __restrict__ B, float* __restrict__ C,
    int M, int N, int K, const float* __restrict__ a_s, const float* __restrict__ a_d,
    float* __restrict__ vs, float* __restrict__ vd){
  __shared__ float As[16][132];
  __shared__ float Bs[16][128];
  int tid = threadIdx.x;
  int tn = tid & 15, tm = tid >> 4;
  int bm = blockIdx.x * 128, bn = blockIdx.y * 128;

  float acc[8][8];
  #pragma unroll
  for (int i = 0; i < 8; i++)
    #pragma unroll
    for (int j = 0; j < 8; j++) acc[i][j] = 0.f;

  int arow = tid >> 2, akc = (tid & 3) * 4;
  int brow = tid >> 4, bcol = (tid & 15) * 8;

  for (int k0 = 0; k0 < K; k0 += 16){
    #pragma unroll
    for (int h = 0; h < 2; h++){
      int r = arow + h * 64;
      int gr = bm + r;
      float4 av = (gr < M) ? *(const float4*)(A + (size_t)gr * K + k0 + akc)
                           : make_float4(0.f, 0.f, 0.f, 0.f);
      As[akc + 0][r] = av.x; As[akc + 1][r] = av.y;
      As[akc + 2][r] = av.z; As[akc + 3][r] = av.w;
    }
    const float* bp = B + (size_t)(k0 + brow) * N + bn + bcol;
    *(float4*)&Bs[brow][bcol]     = *(const float4*)bp;
    *(float4*)&Bs[brow][bcol + 4] = *(const float4*)(bp + 4);
    __syncthreads();

    #pragma unroll
    for (int k = 0; k < 16; k++){
      float4 a0 = *(const float4*)&As[k][tm * 8];
      float4 a1 = *(const float4*)&As[k][tm * 8 + 4];
      float4 b0 = *(const float4*)&Bs[k][tn * 8];
      float4 b1 = *(const float4*)&Bs[k][tn * 8 + 4];
      float a[8] = {a0.x, a0.y, a0.z, a0.w, a1.x, a1.y, a1.z, a1.w};
      float bb[8] = {b0.x, b0.y, b0.z, b0.w, b1.x, b1.y, b1.z, b1.w};
      #pragma unroll
      for (int i = 0; i < 8; i++)
        #pragma unroll
        for (int j = 0; j < 8; j++) acc[i][j] += a[i] * bb[j];
    }
    __syncthreads();
  }
  // C store
  #pragma unroll
  for (int i = 0; i < 8; i++){
    int r = bm + tm * 8 + i;
    if (r < M){
      float* cp = C + (size_t)r * N + bn + tn * 8;
      *(float4*)cp       = make_float4(acc[i][0], acc[i][1], acc[i][2], acc[i][3]);
      *(float4*)(cp + 4) = make_float4(acc[i][4], acc[i][5], acc[i][6], acc[i][7]);
    }
  }
  // fused row dots (partial over this bn tile)
  const float* asp = a_s + bn + tn * 8;
  const float* adp = a_d + bn + tn * 8;
  float4 s0 = *(const float4*)asp, s1 = *(const float4*)(asp + 4);
  float4 d0 = *(const float4*)adp, d1 = *(const float4*)(adp + 4);
  float sv[8] = {s0.x, s0.y, s0.z, s0.w, s1.x, s1.y, s1.z, s1.w};
  float dv[8] = {d0.x, d0.y, d0.z, d0.w, d1.x, d1.y, d1.z, d1.w};
  #pragma unroll
  for (int i = 0; i < 8; i++){
    float ps = 0.f, pd = 0.f;
    #pragma unroll
    for (int j = 0; j < 8; j++){ ps = fmaf(acc[i][j], sv[j], ps); pd = fmaf(acc[i][j], dv[j], pd); }
    ps += __shfl_xor(ps, 1); ps += __shfl_xor(ps, 2); ps += __shfl_xor(ps, 4); ps += __shfl_xor(ps, 8);
    pd += __shfl_xor(pd, 1); pd += __shfl_xor(pd, 2); pd += __shfl_xor(pd, 4); pd += __shfl_xor(pd, 8);
    int r = bm + tm * 8 + i;
    if (tn == 0 && r < M){ atomicAdd(&vs[r], ps); atomicAdd(&vd[r], pd); }
  }
}

// ---------------- fp32 GEMM 64x64 + fused full row-dots (stage 3), BM=64, pipelined ----------------
__global__ __launch_bounds__(256) void k_gemm64_dots(
    const float* __restrict__ A, const float* __restrict__ B, float* __restrict__ C,
    int M, int N, int K, const float* __restrict__ a_s, const float* __restrict__ a_d,
    float* __restrict__ vs, float* __restrict__ vd){
  __shared__ float As[16][68];
  __shared__ float Bs[16][64];
  int tid = threadIdx.x;
  int tn = tid & 15, tm = tid >> 4;
  int bm = blockIdx.x * 64;

  float acc[4][4];
  #pragma unroll
  for (int i = 0; i < 4; i++)
    #pragma unroll
    for (int j = 0; j < 4; j++) acc[i][j] = 0.f;

  int arow = tid >> 2, akc = (tid & 3) * 4;
  int brow = tid >> 4, bcol = (tid & 15) * 4;
  int gr = bm + arow;

  float4 pa, pb;
  pa = (gr < M) ? *(const float4*)(A + (size_t)gr * K + akc) : make_float4(0,0,0,0);
  pb = *(const float4*)(B + (size_t)brow * N + bcol);

  for (int k0 = 0; k0 < K; k0 += 16){
    As[akc + 0][arow] = pa.x; As[akc + 1][arow] = pa.y;
    As[akc + 2][arow] = pa.z; As[akc + 3][arow] = pa.w;
    *(float4*)&Bs[brow][bcol] = pb;
    __syncthreads();

    int k1 = k0 + 16;
    if (k1 < K){
      pa = (gr < M) ? *(const float4*)(A + (size_t)gr * K + k1 + akc) : make_float4(0,0,0,0);
      pb = *(const float4*)(B + (size_t)(k1 + brow) * N + bcol);
    }

    #pragma unroll
    for (int k = 0; k < 16; k++){
      float4 a = *(const float4*)&As[k][tm * 4];
      float4 b = *(const float4*)&Bs[k][tn * 4];
      float av[4] = {a.x, a.y, a.z, a.w};
      float bb[4] = {b.x, b.y, b.z, b.w};
      #pragma unroll
      for (int i = 0; i < 4; i++)
        #pragma unroll
        for (int j = 0; j < 4; j++) acc[i][j] += av[i] * bb[j];
    }
    __syncthreads();
  }
  float4 s = *(const float4*)(a_s + tn * 4);
  float4 d = *(const float4*)(a_d + tn * 4);
  #pragma unroll
  for (int i = 0; i < 4; i++){
    int r = bm + tm * 4 + i;
    if (r < M)
      *(float4*)(C + (size_t)r * N + tn * 4) = make_float4(acc[i][0], acc[i][1], acc[i][2], acc[i][3]);
    float ps = acc[i][0]*s.x + acc[i][1]*s.y + acc[i][2]*s.z + acc[i][3]*s.w;
    float pd = acc[i][0]*d.x + acc[i][1]*d.y + acc[i][2]*d.z + acc[i][3]*d.w;
    ps += __shfl_xor(ps, 1); ps += __shfl_xor(ps, 2); ps += __shfl_xor(ps, 4); ps += __shfl_xor(ps, 8);
    pd += __shfl_xor(pd, 1); pd += __shfl_xor(pd, 2); pd += __shfl_xor(pd, 4); pd += __shfl_xor(pd, 8);
    if (tn == 0 && r < M){ vs[r] = ps; vd[r] = pd; }
  }
}

// ---------------- hypergraph aggregation in 128-dim input space ----------------
__global__ __launch_bounds__(256) void k_hg_edge128(const float* __restrict__ x, const int* __restrict__ off,
                                                    const int* __restrict__ heNodes, float* __restrict__ mout,
                                                    int nhe){
  int wid = (blockIdx.x * blockDim.x + threadIdx.x) >> 6;
  int lane = threadIdx.x & 63;
  if (wid >= nhe) return;
  int s = off[wid], e = off[wid + 1];
  float2 a0 = make_float2(0,0), a1 = a0, a2 = a0, a3 = a0;
  int i = s;
  for (; i + 8 <= e; i += 8){
    int n8[8];
    #pragma unroll
    for (int u = 0; u < 8; u++) n8[u] = heNodes[i + u];
    float2 v8[8];
    #pragma unroll
    for (int u = 0; u < 8; u++) v8[u] = *(const float2*)(x + (size_t)n8[u] * 128 + lane * 2);
    #pragma unroll
    for (int u = 0; u < 8; u++){
      float2* c = (u & 3) == 0 ? &a0 : (u & 3) == 1 ? &a1 : (u & 3) == 2 ? &a2 : &a3;
      c->x += v8[u].x; c->y += v8[u].y;
    }
  }
  for (; i < e; i++){
    int nd = heNodes[i];
    float2 v = *(const float2*)(x + (size_t)nd * 128 + lane * 2);
    a0.x += v.x; a0.y += v.y;
  }
  float inv = (e > s) ? 1.f / (float)(e - s) : 0.f;
  float2 o = make_float2((a0.x + a1.x + a2.x + a3.x) * inv, (a0.y + a1.y + a2.y + a3.y) * inv);
  *(float2*)(mout + (size_t)wid * 128 + lane * 2) = o;
}

__global__ __launch_bounds__(256) void k_hg_node128(const float* __restrict__ m_in, const int* __restrict__ off,
                                                    const int* __restrict__ nHEs, float* __restrict__ out,
                                                    int nn){
  int wid = (blockIdx.x * blockDim.x + threadIdx.x) >> 6;
  int lane = threadIdx.x & 63;
  if (wid >= nn) return;
  int s = off[wid], e = off[wid + 1];
  float2 a0 = make_float2(0,0), a1 = a0, a2 = a0, a3 = a0;
  int i = s;
  for (; i + 4 <= e; i += 4){
    int n0 = nHEs[i], n1 = nHEs[i+1], n2 = nHEs[i+2], n3 = nHEs[i+3];
    float2 v0 = *(const float2*)(m_in + (size_t)n0 * 128 + lane * 2);
    float2 v1 = *(const float2*)(m_in + (size_t)n1 * 128 + lane * 2);
    float2 v2 = *(const float2*)(m_in + (size_t)n2 * 128 + lane * 2);
    float2 v3 = *(const float2*)(m_in + (size_t)n3 * 128 + lane * 2);
    a0.x += v0.x; a0.y += v0.y; a1.x += v1.x; a1.y += v1.y;
    a2.x += v2.x; a2.y += v2.y; a3.x += v3.x; a3.y += v3.y;
  }
  for (; i < e; i++){
    int he = nHEs[i];
    float2 v = *(const float2*)(m_in + (size_t)he * 128 + lane * 2);
    a0.x += v.x; a0.y += v.y;
  }
  float inv = (e > s) ? 1.f / (float)(e - s) : 0.f;
  float2 o = make_float2((a0.x + a1.x + a2.x + a3.x) * inv, (a0.y + a1.y + a2.y + a3.y) * inv);
  *(float2*)(out + (size_t)wid * 128 + lane * 2) = o;
}

// ---------------- GAT aggregation, fused softmax, no max pass, 8x unroll ----------------
__global__ __launch_bounds__(256) void k_gat256(const float* __restrict__ h, const float* __restrict__ asr,
                                                const float* __restrict__ ads, const int* __restrict__ off,
                                                const int* __restrict__ srcIdx, const float* __restrict__ bias,
                                                float* __restrict__ out, int nn){
  int wid = (blockIdx.x * blockDim.x + threadIdx.x) >> 6;
  int lane = threadIdx.x & 63;
  if (wid >= nn) return;
  float ad = ads[wid];
  int s = off[wid], e = off[wid + 1];

  float ssum = 0.f;
  float4 c0 = make_float4(0,0,0,0), c1 = c0, c2 = c0, c3 = c0;
  {
    float e0 = __expf(lrelu(asr[wid] + ad));   // self-loop
    ssum += e0;
    float4 v = *(const float4*)(h + (size_t)wid * 256 + lane * 4);
    c0.x += e0 * v.x; c0.y += e0 * v.y; c0.z += e0 * v.z; c0.w += e0 * v.w;
  }
  int i = s;
  for (; i + 8 <= e; i += 8){
    int n8[8];
    #pragma unroll
    for (int u = 0; u < 8; u++) n8[u] = srcIdx[i + u];
    float f8[8];
    #pragma unroll
    for (int u = 0; u < 8; u++) f8[u] = asr[n8[u]];
    float4 v8[8];
    #pragma unroll
    for (int u = 0; u < 8; u++) v8[u] = *(const float4*)(h + (size_t)n8[u] * 256 + lane * 4);
    #pragma unroll
    for (int u = 0; u < 8; u++){
      float ee = __expf(lrelu(f8[u] + ad));
      ssum += ee;
      float4* c = (u & 3) == 0 ? &c0 : (u & 3) == 1 ? &c1 : (u & 3) == 2 ? &c2 : &c3;
      c->x += ee * v8[u].x; c->y += ee * v8[u].y; c->z += ee * v8[u].z; c->w += ee * v8[u].w;
    }
  }
  for (; i < e; i++){
    int sn = srcIdx[i];
    float ee = __expf(lrelu(asr[sn] + ad));
    ssum += ee;
    float4 v = *(const float4*)(h + (size_t)sn * 256 + lane * 4);
    c0.x += ee * v.x; c0.y += ee * v.y; c0.z += ee * v.z; c0.w += ee * v.w;
  }
  float r = 1.f / (ssum + 1e-16f);
  float4 b = *(const float4*)(bias + lane * 4);
  v4f o;
  o.x = fmaxf((c0.x + c1.x + c2.x + c3.x) * r + b.x, 0.f);
  o.y = fmaxf((c0.y + c1.y + c2.y + c3.y) * r + b.y, 0.f);
  o.z = fmaxf((c0.z + c1.z + c2.z + c3.z) * r + b.z, 0.f);
  o.w = fmaxf((c0.w + c1.w + c2.w + c3.w) * r + b.w, 0.f);
  __builtin_nontemporal_store(o, (v4f*)(out + (size_t)wid * 256 + lane * 4));
}

__global__ __launch_bounds__(256) void k_gat64(const float* __restrict__ h, const float* __restrict__ asr,
                                               const float* __restrict__ ads, const int* __restrict__ off,
                                               const int* __restrict__ srcIdx, const float* __restrict__ bias,
                                               float* __restrict__ out, int nn){
  int wid = (blockIdx.x * blockDim.x + threadIdx.x) >> 6;
  int lane = threadIdx.x & 63;
  if (wid >= nn) return;
  float ad = ads[wid];
  int s = off[wid], e = off[wid + 1];

  float ssum = 0.f;
  float c0 = 0.f, c1 = 0.f, c2 = 0.f, c3 = 0.f;
  {
    float e0 = __expf(lrelu(asr[wid] + ad));
    ssum += e0;
    c0 += e0 * h[(size_t)wid * 64 + lane];
  }
  int i = s;
  for (; i + 8 <= e; i += 8){
    int n8[8];
    #pragma unroll
    for (int u = 0; u < 8; u++) n8[u] = srcIdx[i + u];
    float f8[8], v8[8];
    #pragma unroll
    for (int u = 0; u < 8; u++) f8[u] = asr[n8[u]];
    #pragma unroll
    for (int u = 0; u < 8; u++) v8[u] = h[(size_t)n8[u] * 64 + lane];
    #pragma unroll
    for (int u = 0; u < 8; u++){
      float ee = __expf(lrelu(f8[u] + ad));
      ssum += ee;
      if ((u & 3) == 0) c0 += ee * v8[u];
      else if ((u & 3) == 1) c1 += ee * v8[u];
      else if ((u & 3) == 2) c2 += ee * v8[u];
      else c3 += ee * v8[u];
    }
  }
  for (; i < e; i++){
    int sn = srcIdx[i];
    float ee = __expf(lrelu(asr[sn] + ad));
    ssum += ee;
    c0 += ee * h[(size_t)sn * 64 + lane];
  }
  float r = 1.f / (ssum + 1e-16f);
  out[(size_t)wid * 64 + lane] = fmaxf((c0 + c1 + c2 + c3) * r + bias[lane], 0.f);
}

// ---------------- decode: GEMM-tiled MLP, 128 edges/block ----------------
#define DEC_EPB 128

__device__ __forceinline__ void dec_stageW(float (*Ws)[68], const float* __restrict__ W, int tid){
  #pragma unroll
  for (int i = 0; i < 4; i++){
    int idx = tid + i * 256;
    int r = idx >> 4, c = (idx & 15) * 4;
    *(float4*)&Ws[r][c] = *(const float4*)(W + r * 64 + c);
  }
}

__device__ __forceinline__ void dec_gather(float (*act)[132], const float* __restrict__ z,
                                           const int* __restrict__ idxv, int ebase, int wv, int lane, int L){
  #pragma unroll 4
  for (int t = 0; t < 32; t++){
    int le = wv * 32 + t;
    int e = ebase + le;
    int nd = (e < L) ? idxv[e] : 0;
    act[lane][le] = z[(size_t)nd * 64 + lane];
  }
}

__device__ __forceinline__ void dec_mac64(const float (*act)[132], const float (*Ws)[68],
                                          int tm, int tn, float (&acc)[8][4]){
  #pragma unroll 8
  for (int k = 0; k < 64; k++){
    float4 a0 = *(const float4*)&act[k][tm * 8];
    float4 a1 = *(const float4*)&act[k][tm * 8 + 4];
    float4 b  = *(const float4*)&Ws[k][tn * 4];
    float a[8] = {a0.x, a0.y, a0.z, a0.w, a1.x, a1.y, a1.z, a1.w};
    #pragma unroll
    for (int i = 0; i < 8; i++){
      acc[i][0] = fmaf(a[i], b.x, acc[i][0]);
      acc[i][1] = fmaf(a[i], b.y, acc[i][1]);
      acc[i][2] = fmaf(a[i], b.z, acc[i][2]);
      acc[i][3] = fmaf(a[i], b.w, acc[i][3]);
    }
  }
}

__device__ __forceinline__ void dec_writeback(float (*act)[132], int tm, int tn, const float (&acc)[8][4]){
  #pragma unroll
  for (int j = 0; j < 4; j++)
    #pragma unroll
    for (int i = 0; i < 8; i++)
      act[tn * 4 + j][tm * 8 + i] = fmaxf(acc[i][j], 0.f);
}

__global__ __launch_bounds__(256) void k_decode(const float* __restrict__ z, const int* __restrict__ eli, int L,
    const float* __restrict__ Wm1, const float* __restrict__ bm1,
    const float* __restrict__ Wm2, const float* __restrict__ bm2,
    const float* __restrict__ Wm3, const float* __restrict__ bm3,
    const float* __restrict__ Wm4, const float* __restrict__ bm4,
    float* __restrict__ outPred, float* __restrict__ outProb, float* __restrict__ outLog){
  __shared__ float act[64][132];
  __shared__ float Ws[64][68];
  __shared__ float W4s[192];
  __shared__ float b1s[64], b2s[64], b3s[64], b4s[4];

  int tid = threadIdx.x, lane = tid & 63, wv = tid >> 6;
  int tm = tid >> 4, tn = tid & 15;
  int ebase = blockIdx.x * DEC_EPB;

  if (tid < 64){ b1s[tid] = bm1[tid]; b2s[tid] = bm2[tid]; b3s[tid] = bm3[tid]; }
  if (tid < 3) b4s[tid] = bm4[tid];
  if (tid < 192) W4s[tid] = Wm4[tid];

  dec_stageW(Ws, Wm1, tid);
  dec_gather(act, z, eli, ebase, wv, lane, L);
  __syncthreads();

  float acc[8][4];
  {
    float bx = b1s[tn*4], by = b1s[tn*4+1], bz = b1s[tn*4+2], bw = b1s[tn*4+3];
    #pragma unroll
    for (int i = 0; i < 8; i++){ acc[i][0]=bx; acc[i][1]=by; acc[i][2]=bz; acc[i][3]=bw; }
  }
  dec_mac64(act, Ws, tm, tn, acc);
  __syncthreads();

  dec_stageW(Ws, Wm1 + 4096, tid);
  dec_gather(act, z, eli + L, ebase, wv, lane, L);
  __syncthreads();
  dec_mac64(act, Ws, tm, tn, acc);
  __syncthreads();

  dec_writeback(act, tm, tn, acc);
  dec_stageW(Ws, Wm2, tid);
  __syncthreads();

  {
    float bx = b2s[tn*4], by = b2s[tn*4+1], bz = b2s[tn*4+2], bw = b2s[tn*4+3];
    #pragma unroll
    for (int i = 0; i < 8; i++){ acc[i][0]=bx; acc[i][1]=by; acc[i][2]=bz; acc[i][3]=bw; }
  }
  dec_mac64(act, Ws, tm, tn, acc);
  __syncthreads();
  dec_writeback(act, tm, tn, acc);
  dec_stageW(Ws, Wm3, tid);
  __syncthreads();

  {
    float bx = b3s[tn*4], by = b3s[tn*4+1], bz = b3s[tn*4+2], bw = b3s[tn*4+3];
    #pragma unroll
    for (int i = 0; i < 8; i++){ acc[i][0]=bx; acc[i][1]=by; acc[i][2]=bz; acc[i][3]=bw; }
  }
  dec_mac64(act, Ws, tm, tn, acc);
  __syncthreads();
  dec_writeback(act, tm, tn, acc);
  __syncthreads();

  if (tid < DEC_EPB){
    int e = tid;
    float o0 = b4s[0], o1 = b4s[1], o2 = b4s[2];
    #pragma unroll 8
    for (int k = 0; k < 64; k++){
      float av = act[k][e];
      o0 = fmaf(av, W4s[k*3+0], o0);
      o1 = fmaf(av, W4s[k*3+1], o1);
      o2 = fmaf(av, W4s[k*3+2], o2);
    }
    int eg = ebase + e;
    if (eg < L){
      int am = 0; float best = o0;
      if (o1 > best){ am = 1; best = o1; }
      if (o2 > best){ am = 2; best = o2; }
      outPred[eg] = (float)am;
      outProb[eg] = best;
      outLog[(size_t)eg * 3 + 0] = o0;
      outLog[(size_t)eg * 3 + 1] = o1;
      outLog[(size_t)eg * 3 + 2] = o2;
    }
  }
}

// ---------------- launch ----------------
extern "C" void kernel_launch(void* const* d_in, const int* in_sizes, int n_in,
                              void* d_out, int out_size, void* d_ws, size_t ws_size,
                              hipStream_t stream){
  const float* x      = (const float*)d_in[0];
  const int*   ei     = (const int*)d_in[1];
  const int*   he_node= (const int*)d_in[2];
  const int*   he_edge= (const int*)d_in[3];
  const int*   eli    = (const int*)d_in[4];
  const float* W1  = (const float*)d_in[5];
  const float* b1  = (const float*)d_in[6];
  const float* W2  = (const float*)d_in[7];
  const float* a2s = (const float*)d_in[8];
  const float* a2d = (const float*)d_in[9];
  const float* b2  = (const float*)d_in[10];
  const float* W3  = (const float*)d_in[11];
  const float* a3s = (const float*)d_in[12];
  const float* a3d = (const float*)d_in[13];
  const float* b3  = (const float*)d_in[14];
  const float* Wm1 = (const float*)d_in[15]; const float* bm1 = (const float*)d_in[16];
  const float* Wm2 = (const float*)d_in[17]; const float* bm2 = (const float*)d_in[18];
  const float* Wm3 = (const float*)d_in[19]; const float* bm3 = (const float*)d_in[20];
  const float* Wm4 = (const float*)d_in[21]; const float* bm4 = (const float*)d_in[22];

  const int N   = in_sizes[0] / 128;   // 50000
  const int E   = in_sizes[1] / 2;     // 800000
  const int INC = in_sizes[2];         // 400000
  const int NHE = NHE_CONST;           // 20000
  const int L   = in_sizes[4] / 2;     // 100000

  char* wbase = (char*)d_ws;
  size_t woff = 0;
  auto walloc = [&](size_t bytes) -> void* {
    void* p = wbase + woff;
    woff = (woff + bytes + 255) & ~(size_t)255;
    return p;
  };
  float* pre1   = (float*)walloc((size_t)N * 128 * 4);
  float* mbuf   = (float*)walloc((size_t)NHE * 128 * 4);
  float* h1     = (float*)walloc((size_t)N * 256 * 4);   // also reused as h2
  float* t2     = (float*)walloc((size_t)N * 256 * 4);
  float* t3     = (float*)walloc((size_t)N * 64 * 4);
  float* zbuf   = (float*)walloc((size_t)N * 64 * 4);
  float* vboth  = (float*)walloc((size_t)2 * N * 4);
  int* heOff  = (int*)walloc((size_t)(NHE + 1) * 4);
  int* nOff   = (int*)walloc((size_t)(N + 1) * 4);
  int* dOff   = (int*)walloc((size_t)(N + 1) * 4);
  int* cntAll = (int*)walloc((size_t)(NHE + 2 * N) * 4);
  int* curAll = (int*)walloc((size_t)(NHE + 2 * N) * 4);
  int* heNodes= (int*)walloc((size_t)INC * 4);
  int* nHEs   = (int*)walloc((size_t)INC * 4);
  int* srcIdx = (int*)walloc((size_t)E * 4);
  int* bsumA  = (int*)walloc(64 * 4);
  int* bsumB  = (int*)walloc(64 * 4);
  int* bsumC  = (int*)walloc(64 * 4);

  int* cntHE = cntAll;           int* cntN = cntAll + NHE; int* cntD = cntAll + NHE + N;
  int* curHE = curAll;           int* curN = curAll + NHE; int* curD = curAll + NHE + N;
  float* vsrc = vboth;           float* vdst = vboth + N;
  float* h2 = h1;                // h1 dead after stage-2 GEMM reads it

  const int* srcPtr = ei;
  const int* dstPtr = ei + E;

  // --- CSR build ---
  hipMemsetAsync(cntAll, 0, (size_t)(NHE + 2 * N) * 4, stream);
  hipMemsetAsync(vboth,  0, (size_t)2 * N * 4, stream);
  k_count_all<<<(E + 255) / 256, 256, 0, stream>>>(he_node, he_edge, INC, dstPtr, E, cntN, cntHE, cntD);

  int nbHE = (NHE + 1023) / 1024;
  int nbN  = (N + 1023) / 1024;
  k_scan_sums3<<<dim3(nbN, 3), 256, 0, stream>>>(cntHE, NHE, bsumA, cntN, N, bsumB, cntD, N, bsumC);
  k_scan_bsum3<<<1, 64, 0, stream>>>(bsumA, nbHE, bsumB, nbN, bsumC, nbN);
  k_scan_apply3<<<dim3(nbN, 3), 256, 0, stream>>>(cntHE, NHE, bsumA, heOff, curHE,
                                                  cntN,  N,   bsumB, nOff,  curN,
                                                  cntD,  N,   bsumC, dOff,  curD);
  k_fill_sliced<<<8 * 128, 256, 0, stream>>>(he_node, he_edge, INC, srcPtr, dstPtr, E,
                                             curN, curHE, curD, nHEs, heNodes, srcIdx, N, NHE);

  int gRowA = (N + 127) / 128;
  int gRowB = (N + 63) / 64;
  int gWav  = (N + 3) / 4;

  // --- stage 1: HypergraphConv (aggregate in 128-dim, GEMM last, fused bias+relu) ---
  k_hg_edge128<<<(NHE + 3) / 4, 256, 0, stream>>>(x, heOff, heNodes, mbuf, NHE);
  k_hg_node128<<<gWav, 256, 0, stream>>>(mbuf, nOff, nHEs, pre1, N);
  k_gemm128_bias_relu<<<dim3(gRowA, 2), 256, 0, stream>>>(pre1, W1, h1, N, 256, 128, b1);

  // --- stage 2: GAT 256->256 (dots fused into GEMM) ---
  k_gemm128_dots<<<dim3(gRowA, 2), 256, 0, stream>>>(h1, W2, t2, N, 256, 256, a2s, a2d, vsrc, vdst);
  k_gat256<<<gWav, 256, 0, stream>>>(t2, vsrc, vdst, dOff, srcIdx, b2, h2, N);

  // --- stage 3: GAT 256->64 (dots fused into GEMM) ---
  k_gemm64_dots<<<gRowB, 256, 0, stream>>>(h2, W3, t3, N, 64, 256, a3s, a3d, vsrc, vdst);
  k_gat64<<<gWav, 256, 0, stream>>>(t3, vsrc, vdst, dOff, srcIdx, b3, zbuf, N);

  // --- decode ---
  float* outPred = (float*)d_out;
  float* outProb = outPred + L;
  float* outLog  = outProb + L;
  k_decode<<<(L + DEC_EPB - 1) / DEC_EPB, 256, 0, stream>>>(zbuf, eli, L,
                                    Wm1, bm1, Wm2, bm2, Wm3, bm3, Wm4, bm4,
                                    outPred, outProb, outLog);
}

// Round 11
// 798.072 us; speedup vs baseline: 1.5309x; 1.0022x over previous
//
#include <hip/hip_runtime.h>
#include <math.h>

#define NHE_CONST 20000

typedef float v4f __attribute__((ext_vector_type(4)));

__device__ __forceinline__ float lrelu(float x){ return x >= 0.f ? x : 0.2f * x; }

// ---------------- CSR build (merged) ----------------
__global__ void k_count_all(const int* __restrict__ he_node, const int* __restrict__ he_edge, int inc,
                            const int* __restrict__ dst, int e,
                            int* cntN, int* cntHE, int* cntD){
  int i = blockIdx.x * blockDim.x + threadIdx.x;
  if (i < inc){ atomicAdd(&cntN[he_node[i]], 1); atomicAdd(&cntHE[he_edge[i]], 1); }
  if (i < e) atomicAdd(&cntD[dst[i]], 1);
}

__global__ __launch_bounds__(256) void k_scan_sums3(
    const int* __restrict__ p0, int n0, int* __restrict__ b0,
    const int* __restrict__ p1, int n1, int* __restrict__ b1,
    const int* __restrict__ p2, int n2, int* __restrict__ b2){
  const int* p; int n; int* bs;
  if (blockIdx.y == 0){ p = p0; n = n0; bs = b0; }
  else if (blockIdx.y == 1){ p = p1; n = n1; bs = b1; }
  else { p = p2; n = n2; bs = b2; }
  int nb = (n + 1023) / 1024;
  if ((int)blockIdx.x >= nb) return;
  __shared__ int sm[256];
  int base = blockIdx.x * 1024;
  int v = 0;
  for (int i = threadIdx.x; i < 1024; i += 256){
    int idx = base + i;
    v += (idx < n) ? p[idx] : 0;
  }
  sm[threadIdx.x] = v; __syncthreads();
  for (int d = 128; d > 0; d >>= 1){
    if (threadIdx.x < d) sm[threadIdx.x] += sm[threadIdx.x + d];
    __syncthreads();
  }
  if (threadIdx.x == 0) bs[blockIdx.x] = sm[0];
}

__global__ void k_scan_bsum3(int* b0, int nb0, int* b1, int nb1, int* b2, int nb2){
  int t = threadIdx.x;
  int* bs; int nb;
  if (t == 0){ bs = b0; nb = nb0; }
  else if (t == 1){ bs = b1; nb = nb1; }
  else if (t == 2){ bs = b2; nb = nb2; }
  else return;
  int acc = 0;
  for (int i = 0; i < nb; i++){ int v = bs[i]; bs[i] = acc; acc += v; }
}

__global__ __launch_bounds__(256) void k_scan_apply3(
    const int* __restrict__ c0, int n0, const int* __restrict__ s0, int* __restrict__ o0, int* __restrict__ u0,
    const int* __restrict__ c1, int n1, const int* __restrict__ s1, int* __restrict__ o1, int* __restrict__ u1,
    const int* __restrict__ c2, int n2, const int* __restrict__ s2, int* __restrict__ o2, int* __restrict__ u2){
  const int* cnt; int n; const int* bsum; int* off; int* cur;
  if (blockIdx.y == 0){ cnt = c0; n = n0; bsum = s0; off = o0; cur = u0; }
  else if (blockIdx.y == 1){ cnt = c1; n = n1; bsum = s1; off = o1; cur = u1; }
  else { cnt = c2; n = n2; bsum = s2; off = o2; cur = u2; }
  int nb = (n + 1023) / 1024;
  int b = blockIdx.x;
  if (b >= nb) return;
  __shared__ int sm[256];
  int base = b * 1024 + threadIdx.x * 4;
  int v[4];
  #pragma unroll
  for (int i = 0; i < 4; i++) v[i] = (base + i < n) ? cnt[base + i] : 0;
  int s = v[0] + v[1] + v[2] + v[3];
  sm[threadIdx.x] = s; __syncthreads();
  int x = s;
  for (int d = 1; d < 256; d <<= 1){
    int t = (threadIdx.x >= d) ? sm[threadIdx.x - d] : 0;
    __syncthreads();
    x += t; sm[threadIdx.x] = x;
    __syncthreads();
  }
  int run = x - s + bsum[b];
  #pragma unroll
  for (int i = 0; i < 4; i++){
    if (base + i < n) cur[base + i] = run;
    run += v[i];
    if (base + i < n) off[base + i + 1] = run;
  }
  if (b == 0 && threadIdx.x == 0) off[0] = 0;
}

// Sliced fill: key-range slices pin scatter regions to one XCD's L2 (kills write amp).
__global__ __launch_bounds__(256) void k_fill_sliced(
    const int* __restrict__ he_node, const int* __restrict__ he_edge, int inc,
    const int* __restrict__ src, const int* __restrict__ dst, int e,
    int* curN, int* curHE, int* curD,
    int* __restrict__ nHEs, int* __restrict__ heNodes, int* __restrict__ srcIdx,
    int nN, int nHE){
  int slice = blockIdx.x & 7;
  int group = blockIdx.x >> 3;
  int ngroups = gridDim.x >> 3;
  int sN  = (nN  + 7) >> 3;  int loN  = slice * sN;  int hiN  = min(loN + sN, nN);
  int sHE = (nHE + 7) >> 3;  int loHE = slice * sHE; int hiHE = min(loHE + sHE, nHE);
  int stride = ngroups * 256;
  int start = group * 256 + threadIdx.x;
  for (int i = start; i < e; i += stride){
    int d = dst[i];
    if (d >= loN && d < hiN){
      int p = atomicAdd(&curD[d], 1);
      srcIdx[p] = src[i];
    }
  }
  for (int i = start; i < inc; i += stride){
    int nd = he_node[i], he = he_edge[i];
    if (nd >= loN && nd < hiN){
      int q = atomicAdd(&curN[nd], 1);
      nHEs[q] = he;
    }
    if (he >= loHE && he < hiHE){
      int p = atomicAdd(&curHE[he], 1);
      heNodes[p] = nd;
    }
  }
}

// ---------------- fp32 GEMM BM=128 BN=64, 8x4 tile, register-prefetch, bias+relu ----------------
__global__ __launch_bounds__(256) void k_gemm_b64_bias(
    const float* __restrict__ A, const float* __restrict__ B, float* __restrict__ C,
    int M, int N, int K, const float* __restrict__ bias){
  __shared__ float As[16][132];
  __shared__ float Bs[16][64];
  int tid = threadIdx.x;
  int tn = tid & 15, tm = tid >> 4;
  int bm = blockIdx.x * 128, bn = blockIdx.y * 64;

  float acc[8][4];
  #pragma unroll
  for (int i = 0; i < 8; i++)
    #pragma unroll
    for (int j = 0; j < 4; j++) acc[i][j] = 0.f;

  int arow = tid >> 2, akc = (tid & 3) * 4;
  int brow = tid >> 4, bcol = (tid & 15) * 4;
  int gr0 = bm + arow, gr1 = gr0 + 64;

  float4 pa0, pa1, pb;
  pa0 = (gr0 < M) ? *(const float4*)(A + (size_t)gr0 * K + akc) : make_float4(0,0,0,0);
  pa1 = (gr1 < M) ? *(const float4*)(A + (size_t)gr1 * K + akc) : make_float4(0,0,0,0);
  pb  = *(const float4*)(B + (size_t)brow * N + bn + bcol);

  for (int k0 = 0; k0 < K; k0 += 16){
    As[akc + 0][arow] = pa0.x; As[akc + 1][arow] = pa0.y;
    As[akc + 2][arow] = pa0.z; As[akc + 3][arow] = pa0.w;
    As[akc + 0][arow + 64] = pa1.x; As[akc + 1][arow + 64] = pa1.y;
    As[akc + 2][arow + 64] = pa1.z; As[akc + 3][arow + 64] = pa1.w;
    *(float4*)&Bs[brow][bcol] = pb;
    __syncthreads();

    int k1 = k0 + 16;
    if (k1 < K){
      pa0 = (gr0 < M) ? *(const float4*)(A + (size_t)gr0 * K + k1 + akc) : make_float4(0,0,0,0);
      pa1 = (gr1 < M) ? *(const float4*)(A + (size_t)gr1 * K + k1 + akc) : make_float4(0,0,0,0);
      pb  = *(const float4*)(B + (size_t)(k1 + brow) * N + bn + bcol);
    }

    #pragma unroll
    for (int k = 0; k < 16; k++){
      float4 a0 = *(const float4*)&As[k][tm * 8];
      float4 a1 = *(const float4*)&As[k][tm * 8 + 4];
      float4 b  = *(const float4*)&Bs[k][tn * 4];
      float a[8] = {a0.x, a0.y, a0.z, a0.w, a1.x, a1.y, a1.z, a1.w};
      float bb[4] = {b.x, b.y, b.z, b.w};
      #pragma unroll
      for (int i = 0; i < 8; i++)
        #pragma unroll
        for (int j = 0; j < 4; j++) acc[i][j] += a[i] * bb[j];
    }
    __syncthreads();
  }
  float4 bv = *(const float4*)(bias + bn + tn * 4);
  #pragma unroll
  for (int i = 0; i < 8; i++){
    int r = bm + tm * 8 + i;
    if (r < M){
      *(float4*)(C + (size_t)r * N + bn + tn * 4) =
        make_float4(fmaxf(acc[i][0]+bv.x,0.f), fmaxf(acc[i][1]+bv.y,0.f),
                    fmaxf(acc[i][2]+bv.z,0.f), fmaxf(acc[i][3]+bv.w,0.f));
    }
  }
}

// ---------------- fp32 GEMM BM=128 BN=64, 8x4 tile, register-prefetch, fused row-dots ----------------
__global__ __launch_bounds__(256) void k_gemm_b64_dots(
    const float* __restrict__ A, const float* __restrict__ B, float* __restrict__ C,
    int M, int N, int K, const float* __restrict__ a_s, const float* __restrict__ a_d,
    float* __restrict__ vs, float* __restrict__ vd){
  __shared__ float As[16][132];
  __shared__ float Bs[16][64];
  int tid = threadIdx.x;
  int tn = tid & 15, tm = tid >> 4;
  int bm = blockIdx.x * 128, bn = blockIdx.y * 64;

  float acc[8][4];
  #pragma unroll
  for (int i = 0; i < 8; i++)
    #pragma unroll
    for (int j = 0; j < 4; j++) acc[i][j] = 0.f;

  int arow = tid >> 2, akc = (tid & 3) * 4;
  int brow = tid >> 4, bcol = (tid & 15) * 4;
  int gr0 = bm + arow, gr1 = gr0 + 64;

  float4 pa0, pa1, pb;
  pa0 = (gr0 < M) ? *(const float4*)(A + (size_t)gr0 * K + akc) : make_float4(0,0,0,0);
  pa1 = (gr1 < M) ? *(const float4*)(A + (size_t)gr1 * K + akc) : make_float4(0,0,0,0);
  pb  = *(const float4*)(B + (size_t)brow * N + bn + bcol);

  for (int k0 = 0; k0 < K; k0 += 16){
    As[akc + 0][arow] = pa0.x; As[akc + 1][arow] = pa0.y;
    As[akc + 2][arow] = pa0.z; As[akc + 3][arow] = pa0.w;
    As[akc + 0][arow + 64] = pa1.x; As[akc + 1][arow + 64] = pa1.y;
    As[akc + 2][arow + 64] = pa1.z; As[akc + 3][arow + 64] = pa1.w;
    *(float4*)&Bs[brow][bcol] = pb;
    __syncthreads();

    int k1 = k0 + 16;
    if (k1 < K){
      pa0 = (gr0 < M) ? *(const float4*)(A + (size_t)gr0 * K + k1 + akc) : make_float4(0,0,0,0);
      pa1 = (gr1 < M) ? *(const float4*)(A + (size_t)gr1 * K + k1 + akc) : make_float4(0,0,0,0);
      pb  = *(const float4*)(B + (size_t)(k1 + brow) * N + bn + bcol);
    }

    #pragma unroll
    for (int k = 0; k < 16; k++){
      float4 a0 = *(const float4*)&As[k][tm * 8];
      float4 a1 = *(const float4*)&As[k][tm * 8 + 4];
      float4 b  = *(const float4*)&Bs[k][tn * 4];
      float a[8] = {a0.x, a0.y, a0.z, a0.w, a1.x, a1.y, a1.z, a1.w};
      float bb[4] = {b.x, b.y, b.z, b.w};
      #pragma unroll
      for (int i = 0; i < 8; i++)
        #pragma unroll
        for (int j = 0; j < 4; j++) acc[i][j] += a[i] * bb[j];
    }
    __syncthreads();
  }
  float4 s = *(const float4*)(a_s + bn + tn * 4);
  float4 d = *(const float4*)(a_d + bn + tn * 4);
  #pragma unroll
  for (int i = 0; i < 8; i++){
    int r = bm + tm * 8 + i;
    if (r < M)
      *(float4*)(C + (size_t)r * N + bn + tn * 4) =
        make_float4(acc[i][0], acc[i][1], acc[i][2], acc[i][3]);
    float ps = acc[i][0]*s.x + acc[i][1]*s.y + acc[i][2]*s.z + acc[i][3]*s.w;
    float pd = acc[i][0]*d.x + acc[i][1]*d.y + acc[i][2]*d.z + acc[i][3]*d.w;
    ps += __shfl_xor(ps, 1); ps += __shfl_xor(ps, 2); ps += __shfl_xor(ps, 4); ps += __shfl_xor(ps, 8);
    pd += __shfl_xor(pd, 1); pd += __shfl_xor(pd, 2); pd += __shfl_xor(pd, 4); pd += __shfl_xor(pd, 8);
    if (tn == 0 && r < M){ atomicAdd(&vs[r], ps); atomicAdd(&vd[r], pd); }
  }
}

// ---------------- fp32 GEMM 64x64 + fused full row-dots (stage 3), BM=64, pipelined ----------------
__global__ __launch_bounds__(256) void k_gemm64_dots(
    const float* __restrict__ A, const float* __restrict__ B, float* __restrict__ C,
    int M, int N, int K, const float* __restrict__ a_s, const float* __restrict__ a_d,
    float* __restrict__ vs, float* __restrict__ vd){
  __shared__ float As[16][68];
  __shared__ float Bs[16][64];
  int tid = threadIdx.x;
  int tn = tid & 15, tm = tid >> 4;
  int bm = blockIdx.x * 64;

  float acc[4][4];
  #pragma unroll
  for (int i = 0; i < 4; i++)
    #pragma unroll
    for (int j = 0; j < 4; j++) acc[i][j] = 0.f;

  int arow = tid >> 2, akc = (tid & 3) * 4;
  int brow = tid >> 4, bcol = (tid & 15) * 4;
  int gr = bm + arow;

  float4 pa, pb;
  pa = (gr < M) ? *(const float4*)(A + (size_t)gr * K + akc) : make_float4(0,0,0,0);
  pb = *(const float4*)(B + (size_t)brow * N + bcol);

  for (int k0 = 0; k0 < K; k0 += 16){
    As[akc + 0][arow] = pa.x; As[akc + 1][arow] = pa.y;
    As[akc + 2][arow] = pa.z; As[akc + 3][arow] = pa.w;
    *(float4*)&Bs[brow][bcol] = pb;
    __syncthreads();

    int k1 = k0 + 16;
    if (k1 < K){
      pa = (gr < M) ? *(const float4*)(A + (size_t)gr * K + k1 + akc) : make_float4(0,0,0,0);
      pb = *(const float4*)(B + (size_t)(k1 + brow) * N + bcol);
    }

    #pragma unroll
    for (int k = 0; k < 16; k++){
      float4 a = *(const float4*)&As[k][tm * 4];
      float4 b = *(const float4*)&Bs[k][tn * 4];
      float av[4] = {a.x, a.y, a.z, a.w};
      float bb[4] = {b.x, b.y, b.z, b.w};
      #pragma unroll
      for (int i = 0; i < 4; i++)
        #pragma unroll
        for (int j = 0; j < 4; j++) acc[i][j] += av[i] * bb[j];
    }
    __syncthreads();
  }
  float4 s = *(const float4*)(a_s + tn * 4);
  float4 d = *(const float4*)(a_d + tn * 4);
  #pragma unroll
  for (int i = 0; i < 4; i++){
    int r = bm + tm * 4 + i;
    if (r < M)
      *(float4*)(C + (size_t)r * N + tn * 4) = make_float4(acc[i][0], acc[i][1], acc[i][2], acc[i][3]);
    float ps = acc[i][0]*s.x + acc[i][1]*s.y + acc[i][2]*s.z + acc[i][3]*s.w;
    float pd = acc[i][0]*d.x + acc[i][1]*d.y + acc[i][2]*d.z + acc[i][3]*d.w;
    ps += __shfl_xor(ps, 1); ps += __shfl_xor(ps, 2); ps += __shfl_xor(ps, 4); ps += __shfl_xor(ps, 8);
    pd += __shfl_xor(pd, 1); pd += __shfl_xor(pd, 2); pd += __shfl_xor(pd, 4); pd += __shfl_xor(pd, 8);
    if (tn == 0 && r < M){ vs[r] = ps; vd[r] = pd; }
  }
}

// ---------------- hypergraph aggregation in 128-dim input space ----------------
__global__ __launch_bounds__(256) void k_hg_edge128(const float* __restrict__ x, const int* __restrict__ off,
                                                    const int* __restrict__ heNodes, float* __restrict__ mout,
                                                    int nhe){
  int wid = (blockIdx.x * blockDim.x + threadIdx.x) >> 6;
  int lane = threadIdx.x & 63;
  if (wid >= nhe) return;
  int s = off[wid], e = off[wid + 1];
  float2 a0 = make_float2(0,0), a1 = a0, a2 = a0, a3 = a0;
  int i = s;
  for (; i + 8 <= e; i += 8){
    int n8[8];
    #pragma unroll
    for (int u = 0; u < 8; u++) n8[u] = heNodes[i + u];
    float2 v8[8];
    #pragma unroll
    for (int u = 0; u < 8; u++) v8[u] = *(const float2*)(x + (size_t)n8[u] * 128 + lane * 2);
    #pragma unroll
    for (int u = 0; u < 8; u++){
      float2* c = (u & 3) == 0 ? &a0 : (u & 3) == 1 ? &a1 : (u & 3) == 2 ? &a2 : &a3;
      c->x += v8[u].x; c->y += v8[u].y;
    }
  }
  for (; i < e; i++){
    int nd = heNodes[i];
    float2 v = *(const float2*)(x + (size_t)nd * 128 + lane * 2);
    a0.x += v.x; a0.y += v.y;
  }
  float inv = (e > s) ? 1.f / (float)(e - s) : 0.f;
  float2 o = make_float2((a0.x + a1.x + a2.x + a3.x) * inv, (a0.y + a1.y + a2.y + a3.y) * inv);
  *(float2*)(mout + (size_t)wid * 128 + lane * 2) = o;
}

__global__ __launch_bounds__(256) void k_hg_node128(const float* __restrict__ m_in, const int* __restrict__ off,
                                                    const int* __restrict__ nHEs, float* __restrict__ out,
                                                    int nn){
  int wid = (blockIdx.x * blockDim.x + threadIdx.x) >> 6;
  int lane = threadIdx.x & 63;
  if (wid >= nn) return;
  int s = off[wid], e = off[wid + 1];
  float2 a0 = make_float2(0,0), a1 = a0, a2 = a0, a3 = a0;
  int i = s;
  for (; i + 4 <= e; i += 4){
    int n0 = nHEs[i], n1 = nHEs[i+1], n2 = nHEs[i+2], n3 = nHEs[i+3];
    float2 v0 = *(const float2*)(m_in + (size_t)n0 * 128 + lane * 2);
    float2 v1 = *(const float2*)(m_in + (size_t)n1 * 128 + lane * 2);
    float2 v2 = *(const float2*)(m_in + (size_t)n2 * 128 + lane * 2);
    float2 v3 = *(const float2*)(m_in + (size_t)n3 * 128 + lane * 2);
    a0.x += v0.x; a0.y += v0.y; a1.x += v1.x; a1.y += v1.y;
    a2.x += v2.x; a2.y += v2.y; a3.x += v3.x; a3.y += v3.y;
  }
  for (; i < e; i++){
    int he = nHEs[i];
    float2 v = *(const float2*)(m_in + (size_t)he * 128 + lane * 2);
    a0.x += v.x; a0.y += v.y;
  }
  float inv = (e > s) ? 1.f / (float)(e - s) : 0.f;
  float2 o = make_float2((a0.x + a1.x + a2.x + a3.x) * inv, (a0.y + a1.y + a2.y + a3.y) * inv);
  *(float2*)(out + (size_t)wid * 128 + lane * 2) = o;
}

// ---------------- GAT aggregation, fused softmax, no max pass, 8x unroll ----------------
__global__ __launch_bounds__(256) void k_gat256(const float* __restrict__ h, const float* __restrict__ asr,
                                                const float* __restrict__ ads, const int* __restrict__ off,
                                                const int* __restrict__ srcIdx, const float* __restrict__ bias,
                                                float* __restrict__ out, int nn){
  int wid = (blockIdx.x * blockDim.x + threadIdx.x) >> 6;
  int lane = threadIdx.x & 63;
  if (wid >= nn) return;
  float ad = ads[wid];
  int s = off[wid], e = off[wid + 1];

  float ssum = 0.f;
  float4 c0 = make_float4(0,0,0,0), c1 = c0, c2 = c0, c3 = c0;
  {
    float e0 = __expf(lrelu(asr[wid] + ad));   // self-loop
    ssum += e0;
    float4 v = *(const float4*)(h + (size_t)wid * 256 + lane * 4);
    c0.x += e0 * v.x; c0.y += e0 * v.y; c0.z += e0 * v.z; c0.w += e0 * v.w;
  }
  int i = s;
  for (; i + 8 <= e; i += 8){
    int n8[8];
    #pragma unroll
    for (int u = 0; u < 8; u++) n8[u] = srcIdx[i + u];
    float f8[8];
    #pragma unroll
    for (int u = 0; u < 8; u++) f8[u] = asr[n8[u]];
    float4 v8[8];
    #pragma unroll
    for (int u = 0; u < 8; u++) v8[u] = *(const float4*)(h + (size_t)n8[u] * 256 + lane * 4);
    #pragma unroll
    for (int u = 0; u < 8; u++){
      float ee = __expf(lrelu(f8[u] + ad));
      ssum += ee;
      float4* c = (u & 3) == 0 ? &c0 : (u & 3) == 1 ? &c1 : (u & 3) == 2 ? &c2 : &c3;
      c->x += ee * v8[u].x; c->y += ee * v8[u].y; c->z += ee * v8[u].z; c->w += ee * v8[u].w;
    }
  }
  for (; i < e; i++){
    int sn = srcIdx[i];
    float ee = __expf(lrelu(asr[sn] + ad));
    ssum += ee;
    float4 v = *(const float4*)(h + (size_t)sn * 256 + lane * 4);
    c0.x += ee * v.x; c0.y += ee * v.y; c0.z += ee * v.z; c0.w += ee * v.w;
  }
  float r = 1.f / (ssum + 1e-16f);
  float4 b = *(const float4*)(bias + lane * 4);
  v4f o;
  o.x = fmaxf((c0.x + c1.x + c2.x + c3.x) * r + b.x, 0.f);
  o.y = fmaxf((c0.y + c1.y + c2.y + c3.y) * r + b.y, 0.f);
  o.z = fmaxf((c0.z + c1.z + c2.z + c3.z) * r + b.z, 0.f);
  o.w = fmaxf((c0.w + c1.w + c2.w + c3.w) * r + b.w, 0.f);
  __builtin_nontemporal_store(o, (v4f*)(out + (size_t)wid * 256 + lane * 4));
}

__global__ __launch_bounds__(256) void k_gat64(const float* __restrict__ h, const float* __restrict__ asr,
                                               const float* __restrict__ ads, const int* __restrict__ off,
                                               const int* __restrict__ srcIdx, const float* __restrict__ bias,
                                               float* __restrict__ out, int nn){
  int wid = (blockIdx.x * blockDim.x + threadIdx.x) >> 6;
  int lane = threadIdx.x & 63;
  if (wid >= nn) return;
  float ad = ads[wid];
  int s = off[wid], e = off[wid + 1];

  float ssum = 0.f;
  float c0 = 0.f, c1 = 0.f, c2 = 0.f, c3 = 0.f;
  {
    float e0 = __expf(lrelu(asr[wid] + ad));
    ssum += e0;
    c0 += e0 * h[(size_t)wid * 64 + lane];
  }
  int i = s;
  for (; i + 8 <= e; i += 8){
    int n8[8];
    #pragma unroll
    for (int u = 0; u < 8; u++) n8[u] = srcIdx[i + u];
    float f8[8], v8[8];
    #pragma unroll
    for (int u = 0; u < 8; u++) f8[u] = asr[n8[u]];
    #pragma unroll
    for (int u = 0; u < 8; u++) v8[u] = h[(size_t)n8[u] * 64 + lane];
    #pragma unroll
    for (int u = 0; u < 8; u++){
      float ee = __expf(lrelu(f8[u] + ad));
      ssum += ee;
      if ((u & 3) == 0) c0 += ee * v8[u];
      else if ((u & 3) == 1) c1 += ee * v8[u];
      else if ((u & 3) == 2) c2 += ee * v8[u];
      else c3 += ee * v8[u];
    }
  }
  for (; i < e; i++){
    int sn = srcIdx[i];
    float ee = __expf(lrelu(asr[sn] + ad));
    ssum += ee;
    c0 += ee * h[(size_t)sn * 64 + lane];
  }
  float r = 1.f / (ssum + 1e-16f);
  out[(size_t)wid * 64 + lane] = fmaxf((c0 + c1 + c2 + c3) * r + bias[lane], 0.f);
}

// ---------------- decode: GEMM-tiled MLP, 128 edges/block ----------------
#define DEC_EPB 128

__device__ __forceinline__ void dec_stageW(float (*Ws)[68], const float* __restrict__ W, int tid){
  #pragma unroll
  for (int i = 0; i < 4; i++){
    int idx = tid + i * 256;
    int r = idx >> 4, c = (idx & 15) * 4;
    *(float4*)&Ws[r][c] = *(const float4*)(W + r * 64 + c);
  }
}

__device__ __forceinline__ void dec_gather(float (*act)[132], const float* __restrict__ z,
                                           const int* __restrict__ idxv, int ebase, int wv, int lane, int L){
  #pragma unroll 4
  for (int t = 0; t < 32; t++){
    int le = wv * 32 + t;
    int e = ebase + le;
    int nd = (e < L) ? idxv[e] : 0;
    act[lane][le] = z[(size_t)nd * 64 + lane];
  }
}

__device__ __forceinline__ void dec_mac64(const float (*act)[132], const float (*Ws)[68],
                                          int tm, int tn, float (&acc)[8][4]){
  #pragma unroll 8
  for (int k = 0; k < 64; k++){
    float4 a0 = *(const float4*)&act[k][tm * 8];
    float4 a1 = *(const float4*)&act[k][tm * 8 + 4];
    float4 b  = *(const float4*)&Ws[k][tn * 4];
    float a[8] = {a0.x, a0.y, a0.z, a0.w, a1.x, a1.y, a1.z, a1.w};
    #pragma unroll
    for (int i = 0; i < 8; i++){
      acc[i][0] = fmaf(a[i], b.x, acc[i][0]);
      acc[i][1] = fmaf(a[i], b.y, acc[i][1]);
      acc[i][2] = fmaf(a[i], b.z, acc[i][2]);
      acc[i][3] = fmaf(a[i], b.w, acc[i][3]);
    }
  }
}

__device__ __forceinline__ void dec_writeback(float (*act)[132], int tm, int tn, const float (&acc)[8][4]){
  #pragma unroll
  for (int j = 0; j < 4; j++)
    #pragma unroll
    for (int i = 0; i < 8; i++)
      act[tn * 4 + j][tm * 8 + i] = fmaxf(acc[i][j], 0.f);
}

__global__ __launch_bounds__(256) void k_decode(const float* __restrict__ z, const int* __restrict__ eli, int L,
    const float* __restrict__ Wm1, const float* __restrict__ bm1,
    const float* __restrict__ Wm2, const float* __restrict__ bm2,
    const float* __restrict__ Wm3, const float* __restrict__ bm3,
    const float* __restrict__ Wm4, const float* __restrict__ bm4,
    float* __restrict__ outPred, float* __restrict__ outProb, float* __restrict__ outLog){
  __shared__ float act[64][132];
  __shared__ float Ws[64][68];
  __shared__ float W4s[192];
  __shared__ float b1s[64], b2s[64], b3s[64], b4s[4];

  int tid = threadIdx.x, lane = tid & 63, wv = tid >> 6;
  int tm = tid >> 4, tn = tid & 15;
  int ebase = blockIdx.x * DEC_EPB;

  if (tid < 64){ b1s[tid] = bm1[tid]; b2s[tid] = bm2[tid]; b3s[tid] = bm3[tid]; }
  if (tid < 3) b4s[tid] = bm4[tid];
  if (tid < 192) W4s[tid] = Wm4[tid];

  dec_stageW(Ws, Wm1, tid);
  dec_gather(act, z, eli, ebase, wv, lane, L);
  __syncthreads();

  float acc[8][4];
  {
    float bx = b1s[tn*4], by = b1s[tn*4+1], bz = b1s[tn*4+2], bw = b1s[tn*4+3];
    #pragma unroll
    for (int i = 0; i < 8; i++){ acc[i][0]=bx; acc[i][1]=by; acc[i][2]=bz; acc[i][3]=bw; }
  }
  dec_mac64(act, Ws, tm, tn, acc);
  __syncthreads();

  dec_stageW(Ws, Wm1 + 4096, tid);
  dec_gather(act, z, eli + L, ebase, wv, lane, L);
  __syncthreads();
  dec_mac64(act, Ws, tm, tn, acc);
  __syncthreads();

  dec_writeback(act, tm, tn, acc);
  dec_stageW(Ws, Wm2, tid);
  __syncthreads();

  {
    float bx = b2s[tn*4], by = b2s[tn*4+1], bz = b2s[tn*4+2], bw = b2s[tn*4+3];
    #pragma unroll
    for (int i = 0; i < 8; i++){ acc[i][0]=bx; acc[i][1]=by; acc[i][2]=bz; acc[i][3]=bw; }
  }
  dec_mac64(act, Ws, tm, tn, acc);
  __syncthreads();
  dec_writeback(act, tm, tn, acc);
  dec_stageW(Ws, Wm3, tid);
  __syncthreads();

  {
    float bx = b3s[tn*4], by = b3s[tn*4+1], bz = b3s[tn*4+2], bw = b3s[tn*4+3];
    #pragma unroll
    for (int i = 0; i < 8; i++){ acc[i][0]=bx; acc[i][1]=by; acc[i][2]=bz; acc[i][3]=bw; }
  }
  dec_mac64(act, Ws, tm, tn, acc);
  __syncthreads();
  dec_writeback(act, tm, tn, acc);
  __syncthreads();

  if (tid < DEC_EPB){
    int e = tid;
    float o0 = b4s[0], o1 = b4s[1], o2 = b4s[2];
    #pragma unroll 8
    for (int k = 0; k < 64; k++){
      float av = act[k][e];
      o0 = fmaf(av, W4s[k*3+0], o0);
      o1 = fmaf(av, W4s[k*3+1], o1);
      o2 = fmaf(av, W4s[k*3+2], o2);
    }
    int eg = ebase + e;
    if (eg < L){
      int am = 0; float best = o0;
      if (o1 > best){ am = 1; best = o1; }
      if (o2 > best){ am = 2; best = o2; }
      outPred[eg] = (float)am;
      outProb[eg] = best;
      outLog[(size_t)eg * 3 + 0] = o0;
      outLog[(size_t)eg * 3 + 1] = o1;
      outLog[(size_t)eg * 3 + 2] = o2;
    }
  }
}

// ---------------- launch ----------------
extern "C" void kernel_launch(void* const* d_in, const int* in_sizes, int n_in,
                              void* d_out, int out_size, void* d_ws, size_t ws_size,
                              hipStream_t stream){
  const float* x      = (const float*)d_in[0];
  const int*   ei     = (const int*)d_in[1];
  const int*   he_node= (const int*)d_in[2];
  const int*   he_edge= (const int*)d_in[3];
  const int*   eli    = (const int*)d_in[4];
  const float* W1  = (const float*)d_in[5];
  const float* b1  = (const float*)d_in[6];
  const float* W2  = (const float*)d_in[7];
  const float* a2s = (const float*)d_in[8];
  const float* a2d = (const float*)d_in[9];
  const float* b2  = (const float*)d_in[10];
  const float* W3  = (const float*)d_in[11];
  const float* a3s = (const float*)d_in[12];
  const float* a3d = (const float*)d_in[13];
  const float* b3  = (const float*)d_in[14];
  const float* Wm1 = (const float*)d_in[15]; const float* bm1 = (const float*)d_in[16];
  const float* Wm2 = (const float*)d_in[17]; const float* bm2 = (const float*)d_in[18];
  const float* Wm3 = (const float*)d_in[19]; const float* bm3 = (const float*)d_in[20];
  const float* Wm4 = (const float*)d_in[21]; const float* bm4 = (const float*)d_in[22];

  const int N   = in_sizes[0] / 128;   // 50000
  const int E   = in_sizes[1] / 2;     // 800000
  const int INC = in_sizes[2];         // 400000
  const int NHE = NHE_CONST;           // 20000
  const int L   = in_sizes[4] / 2;     // 100000

  char* wbase = (char*)d_ws;
  size_t woff = 0;
  auto walloc = [&](size_t bytes) -> void* {
    void* p = wbase + woff;
    woff = (woff + bytes + 255) & ~(size_t)255;
    return p;
  };
  float* pre1   = (float*)walloc((size_t)N * 128 * 4);
  float* mbuf   = (float*)walloc((size_t)NHE * 128 * 4);
  float* h1     = (float*)walloc((size_t)N * 256 * 4);   // also reused as h2
  float* t2     = (float*)walloc((size_t)N * 256 * 4);
  float* t3     = (float*)walloc((size_t)N * 64 * 4);
  float* zbuf   = (float*)walloc((size_t)N * 64 * 4);
  float* vboth  = (float*)walloc((size_t)2 * N * 4);
  int* heOff  = (int*)walloc((size_t)(NHE + 1) * 4);
  int* nOff   = (int*)walloc((size_t)(N + 1) * 4);
  int* dOff   = (int*)walloc((size_t)(N + 1) * 4);
  int* cntAll = (int*)walloc((size_t)(NHE + 2 * N) * 4);
  int* curAll = (int*)walloc((size_t)(NHE + 2 * N) * 4);
  int* heNodes= (int*)walloc((size_t)INC * 4);
  int* nHEs   = (int*)walloc((size_t)INC * 4);
  int* srcIdx = (int*)walloc((size_t)E * 4);
  int* bsumA  = (int*)walloc(64 * 4);
  int* bsumB  = (int*)walloc(64 * 4);
  int* bsumC  = (int*)walloc(64 * 4);

  int* cntHE = cntAll;           int* cntN = cntAll + NHE; int* cntD = cntAll + NHE + N;
  int* curHE = curAll;           int* curN = curAll + NHE; int* curD = curAll + NHE + N;
  float* vsrc = vboth;           float* vdst = vboth + N;
  float* h2 = h1;                // h1 dead after stage-2 GEMM reads it

  const int* srcPtr = ei;
  const int* dstPtr = ei + E;

  // --- CSR build ---
  hipMemsetAsync(cntAll, 0, (size_t)(NHE + 2 * N) * 4, stream);
  hipMemsetAsync(vboth,  0, (size_t)2 * N * 4, stream);
  k_count_all<<<(E + 255) / 256, 256, 0, stream>>>(he_node, he_edge, INC, dstPtr, E, cntN, cntHE, cntD);

  int nbHE = (NHE + 1023) / 1024;
  int nbN  = (N + 1023) / 1024;
  k_scan_sums3<<<dim3(nbN, 3), 256, 0, stream>>>(cntHE, NHE, bsumA, cntN, N, bsumB, cntD, N, bsumC);
  k_scan_bsum3<<<1, 64, 0, stream>>>(bsumA, nbHE, bsumB, nbN, bsumC, nbN);
  k_scan_apply3<<<dim3(nbN, 3), 256, 0, stream>>>(cntHE, NHE, bsumA, heOff, curHE,
                                                  cntN,  N,   bsumB, nOff,  curN,
                                                  cntD,  N,   bsumC, dOff,  curD);
  k_fill_sliced<<<8 * 128, 256, 0, stream>>>(he_node, he_edge, INC, srcPtr, dstPtr, E,
                                             curN, curHE, curD, nHEs, heNodes, srcIdx, N, NHE);

  int gRowA = (N + 127) / 128;
  int gRowB = (N + 63) / 64;
  int gWav  = (N + 3) / 4;

  // --- stage 1: HypergraphConv (aggregate in 128-dim, GEMM last, fused bias+relu) ---
  k_hg_edge128<<<(NHE + 3) / 4, 256, 0, stream>>>(x, heOff, heNodes, mbuf, NHE);
  k_hg_node128<<<gWav, 256, 0, stream>>>(mbuf, nOff, nHEs, pre1, N);
  k_gemm_b64_bias<<<dim3(gRowA, 4), 256, 0, stream>>>(pre1, W1, h1, N, 256, 128, b1);

  // --- stage 2: GAT 256->256 (dots fused into GEMM) ---
  k_gemm_b64_dots<<<dim3(gRowA, 4), 256, 0, stream>>>(h1, W2, t2, N, 256, 256, a2s, a2d, vsrc, vdst);
  k_gat256<<<gWav, 256, 0, stream>>>(t2, vsrc, vdst, dOff, srcIdx, b2, h2, N);

  // --- stage 3: GAT 256->64 (dots fused into GEMM) ---
  k_gemm64_dots<<<gRowB, 256, 0, stream>>>(h2, W3, t3, N, 64, 256, a3s, a3d, vsrc, vdst);
  k_gat64<<<gWav, 256, 0, stream>>>(t3, vsrc, vdst, dOff, srcIdx, b3, zbuf, N);

  // --- decode ---
  float* outPred = (float*)d_out;
  float* outProb = outPred + L;
  float* outLog  = outProb + L;
  k_decode<<<(L + DEC_EPB - 1) / DEC_EPB, 256, 0, stream>>>(zbuf, eli, L,
                                    Wm1, bm1, Wm2, bm2, Wm3, bm3, Wm4, bm4,
                                    outPred, outProb, outLog);
}

// Round 12
// 724.727 us; speedup vs baseline: 1.6859x; 1.1012x over previous
//
#include <hip/hip_runtime.h>
#include <math.h>

#define NHE_CONST 20000

typedef float v4f __attribute__((ext_vector_type(4)));

__device__ __forceinline__ float lrelu(float x){ return x >= 0.f ? x : 0.2f * x; }

// ---------------- CSR build (merged) ----------------
__global__ void k_count_all(const int* __restrict__ he_node, const int* __restrict__ he_edge, int inc,
                            const int* __restrict__ dst, int e,
                            int* cntN, int* cntHE, int* cntD){
  int i = blockIdx.x * blockDim.x + threadIdx.x;
  if (i < inc){ atomicAdd(&cntN[he_node[i]], 1); atomicAdd(&cntHE[he_edge[i]], 1); }
  if (i < e) atomicAdd(&cntD[dst[i]], 1);
}

__global__ __launch_bounds__(256) void k_scan_sums3(
    const int* __restrict__ p0, int n0, int* __restrict__ b0,
    const int* __restrict__ p1, int n1, int* __restrict__ b1,
    const int* __restrict__ p2, int n2, int* __restrict__ b2){
  const int* p; int n; int* bs;
  if (blockIdx.y == 0){ p = p0; n = n0; bs = b0; }
  else if (blockIdx.y == 1){ p = p1; n = n1; bs = b1; }
  else { p = p2; n = n2; bs = b2; }
  int nb = (n + 1023) / 1024;
  if ((int)blockIdx.x >= nb) return;
  __shared__ int sm[256];
  int base = blockIdx.x * 1024;
  int v = 0;
  for (int i = threadIdx.x; i < 1024; i += 256){
    int idx = base + i;
    v += (idx < n) ? p[idx] : 0;
  }
  sm[threadIdx.x] = v; __syncthreads();
  for (int d = 128; d > 0; d >>= 1){
    if (threadIdx.x < d) sm[threadIdx.x] += sm[threadIdx.x + d];
    __syncthreads();
  }
  if (threadIdx.x == 0) bs[blockIdx.x] = sm[0];
}

__global__ void k_scan_bsum3(int* b0, int nb0, int* b1, int nb1, int* b2, int nb2){
  int t = threadIdx.x;
  int* bs; int nb;
  if (t == 0){ bs = b0; nb = nb0; }
  else if (t == 1){ bs = b1; nb = nb1; }
  else if (t == 2){ bs = b2; nb = nb2; }
  else return;
  int acc = 0;
  for (int i = 0; i < nb; i++){ int v = bs[i]; bs[i] = acc; acc += v; }
}

__global__ __launch_bounds__(256) void k_scan_apply3(
    const int* __restrict__ c0, int n0, const int* __restrict__ s0, int* __restrict__ o0, int* __restrict__ u0,
    const int* __restrict__ c1, int n1, const int* __restrict__ s1, int* __restrict__ o1, int* __restrict__ u1,
    const int* __restrict__ c2, int n2, const int* __restrict__ s2, int* __restrict__ o2, int* __restrict__ u2){
  const int* cnt; int n; const int* bsum; int* off; int* cur;
  if (blockIdx.y == 0){ cnt = c0; n = n0; bsum = s0; off = o0; cur = u0; }
  else if (blockIdx.y == 1){ cnt = c1; n = n1; bsum = s1; off = o1; cur = u1; }
  else { cnt = c2; n = n2; bsum = s2; off = o2; cur = u2; }
  int nb = (n + 1023) / 1024;
  int b = blockIdx.x;
  if (b >= nb) return;
  __shared__ int sm[256];
  int base = b * 1024 + threadIdx.x * 4;
  int v[4];
  #pragma unroll
  for (int i = 0; i < 4; i++) v[i] = (base + i < n) ? cnt[base + i] : 0;
  int s = v[0] + v[1] + v[2] + v[3];
  sm[threadIdx.x] = s; __syncthreads();
  int x = s;
  for (int d = 1; d < 256; d <<= 1){
    int t = (threadIdx.x >= d) ? sm[threadIdx.x - d] : 0;
    __syncthreads();
    x += t; sm[threadIdx.x] = x;
    __syncthreads();
  }
  int run = x - s + bsum[b];
  #pragma unroll
  for (int i = 0; i < 4; i++){
    if (base + i < n) cur[base + i] = run;
    run += v[i];
    if (base + i < n) off[base + i + 1] = run;
  }
  if (b == 0 && threadIdx.x == 0) off[0] = 0;
}

// Sliced fill: key-range slices pin scatter regions to one XCD's L2 (kills write amp).
__global__ __launch_bounds__(256) void k_fill_sliced(
    const int* __restrict__ he_node, const int* __restrict__ he_edge, int inc,
    const int* __restrict__ src, const int* __restrict__ dst, int e,
    int* curN, int* curHE, int* curD,
    int* __restrict__ nHEs, int* __restrict__ heNodes, int* __restrict__ srcIdx,
    int nN, int nHE){
  int slice = blockIdx.x & 7;
  int group = blockIdx.x >> 3;
  int ngroups = gridDim.x >> 3;
  int sN  = (nN  + 7) >> 3;  int loN  = slice * sN;  int hiN  = min(loN + sN, nN);
  int sHE = (nHE + 7) >> 3;  int loHE = slice * sHE; int hiHE = min(loHE + sHE, nHE);
  int stride = ngroups * 256;
  int start = group * 256 + threadIdx.x;
  for (int i = start; i < e; i += stride){
    int d = dst[i];
    if (d >= loN && d < hiN){
      int p = atomicAdd(&curD[d], 1);
      srcIdx[p] = src[i];
    }
  }
  for (int i = start; i < inc; i += stride){
    int nd = he_node[i], he = he_edge[i];
    if (nd >= loN && nd < hiN){
      int q = atomicAdd(&curN[nd], 1);
      nHEs[q] = he;
    }
    if (he >= loHE && he < hiHE){
      int p = atomicAdd(&curHE[he], 1);
      heNodes[p] = nd;
    }
  }
}

// ---------------- fp32 GEMM BM=128 BN=64, 8x4 tile, register-prefetch, bias+relu ----------------
__global__ __launch_bounds__(256) void k_gemm_b64_bias(
    const float* __restrict__ A, const float* __restrict__ B, float* __restrict__ C,
    int M, int N, int K, const float* __restrict__ bias){
  __shared__ float As[16][132];
  __shared__ float Bs[16][64];
  int tid = threadIdx.x;
  int tn = tid & 15, tm = tid >> 4;
  int bm = blockIdx.x * 128, bn = blockIdx.y * 64;

  float acc[8][4];
  #pragma unroll
  for (int i = 0; i < 8; i++)
    #pragma unroll
    for (int j = 0; j < 4; j++) acc[i][j] = 0.f;

  int arow = tid >> 2, akc = (tid & 3) * 4;
  int brow = tid >> 4, bcol = (tid & 15) * 4;
  int gr0 = bm + arow, gr1 = gr0 + 64;

  float4 pa0, pa1, pb;
  pa0 = (gr0 < M) ? *(const float4*)(A + (size_t)gr0 * K + akc) : make_float4(0,0,0,0);
  pa1 = (gr1 < M) ? *(const float4*)(A + (size_t)gr1 * K + akc) : make_float4(0,0,0,0);
  pb  = *(const float4*)(B + (size_t)brow * N + bn + bcol);

  for (int k0 = 0; k0 < K; k0 += 16){
    As[akc + 0][arow] = pa0.x; As[akc + 1][arow] = pa0.y;
    As[akc + 2][arow] = pa0.z; As[akc + 3][arow] = pa0.w;
    As[akc + 0][arow + 64] = pa1.x; As[akc + 1][arow + 64] = pa1.y;
    As[akc + 2][arow + 64] = pa1.z; As[akc + 3][arow + 64] = pa1.w;
    *(float4*)&Bs[brow][bcol] = pb;
    __syncthreads();

    int k1 = k0 + 16;
    if (k1 < K){
      pa0 = (gr0 < M) ? *(const float4*)(A + (size_t)gr0 * K + k1 + akc) : make_float4(0,0,0,0);
      pa1 = (gr1 < M) ? *(const float4*)(A + (size_t)gr1 * K + k1 + akc) : make_float4(0,0,0,0);
      pb  = *(const float4*)(B + (size_t)(k1 + brow) * N + bn + bcol);
    }

    #pragma unroll
    for (int k = 0; k < 16; k++){
      float4 a0 = *(const float4*)&As[k][tm * 8];
      float4 a1 = *(const float4*)&As[k][tm * 8 + 4];
      float4 b  = *(const float4*)&Bs[k][tn * 4];
      float a[8] = {a0.x, a0.y, a0.z, a0.w, a1.x, a1.y, a1.z, a1.w};
      float bb[4] = {b.x, b.y, b.z, b.w};
      #pragma unroll
      for (int i = 0; i < 8; i++)
        #pragma unroll
        for (int j = 0; j < 4; j++) acc[i][j] += a[i] * bb[j];
    }
    __syncthreads();
  }
  float4 bv = *(const float4*)(bias + bn + tn * 4);
  #pragma unroll
  for (int i = 0; i < 8; i++){
    int r = bm + tm * 8 + i;
    if (r < M){
      *(float4*)(C + (size_t)r * N + bn + tn * 4) =
        make_float4(fmaxf(acc[i][0]+bv.x,0.f), fmaxf(acc[i][1]+bv.y,0.f),
                    fmaxf(acc[i][2]+bv.z,0.f), fmaxf(acc[i][3]+bv.w,0.f));
    }
  }
}

// ---------------- fp32 GEMM BM=128 BN=64, 8x4 tile, register-prefetch, fused row-dots ----------------
__global__ __launch_bounds__(256) void k_gemm_b64_dots(
    const float* __restrict__ A, const float* __restrict__ B, float* __restrict__ C,
    int M, int N, int K, const float* __restrict__ a_s, const float* __restrict__ a_d,
    float* __restrict__ vs, float* __restrict__ vd){
  __shared__ float As[16][132];
  __shared__ float Bs[16][64];
  int tid = threadIdx.x;
  int tn = tid & 15, tm = tid >> 4;
  int bm = blockIdx.x * 128, bn = blockIdx.y * 64;

  float acc[8][4];
  #pragma unroll
  for (int i = 0; i < 8; i++)
    #pragma unroll
    for (int j = 0; j < 4; j++) acc[i][j] = 0.f;

  int arow = tid >> 2, akc = (tid & 3) * 4;
  int brow = tid >> 4, bcol = (tid & 15) * 4;
  int gr0 = bm + arow, gr1 = gr0 + 64;

  float4 pa0, pa1, pb;
  pa0 = (gr0 < M) ? *(const float4*)(A + (size_t)gr0 * K + akc) : make_float4(0,0,0,0);
  pa1 = (gr1 < M) ? *(const float4*)(A + (size_t)gr1 * K + akc) : make_float4(0,0,0,0);
  pb  = *(const float4*)(B + (size_t)brow * N + bn + bcol);

  for (int k0 = 0; k0 < K; k0 += 16){
    As[akc + 0][arow] = pa0.x; As[akc + 1][arow] = pa0.y;
    As[akc + 2][arow] = pa0.z; As[akc + 3][arow] = pa0.w;
    As[akc + 0][arow + 64] = pa1.x; As[akc + 1][arow + 64] = pa1.y;
    As[akc + 2][arow + 64] = pa1.z; As[akc + 3][arow + 64] = pa1.w;
    *(float4*)&Bs[brow][bcol] = pb;
    __syncthreads();

    int k1 = k0 + 16;
    if (k1 < K){
      pa0 = (gr0 < M) ? *(const float4*)(A + (size_t)gr0 * K + k1 + akc) : make_float4(0,0,0,0);
      pa1 = (gr1 < M) ? *(const float4*)(A + (size_t)gr1 * K + k1 + akc) : make_float4(0,0,0,0);
      pb  = *(const float4*)(B + (size_t)(k1 + brow) * N + bn + bcol);
    }

    #pragma unroll
    for (int k = 0; k < 16; k++){
      float4 a0 = *(const float4*)&As[k][tm * 8];
      float4 a1 = *(const float4*)&As[k][tm * 8 + 4];
      float4 b  = *(const float4*)&Bs[k][tn * 4];
      float a[8] = {a0.x, a0.y, a0.z, a0.w, a1.x, a1.y, a1.z, a1.w};
      float bb[4] = {b.x, b.y, b.z, b.w};
      #pragma unroll
      for (int i = 0; i < 8; i++)
        #pragma unroll
        for (int j = 0; j < 4; j++) acc[i][j] += a[i] * bb[j];
    }
    __syncthreads();
  }
  float4 s = *(const float4*)(a_s + bn + tn * 4);
  float4 d = *(const float4*)(a_d + bn + tn * 4);
  #pragma unroll
  for (int i = 0; i < 8; i++){
    int r = bm + tm * 8 + i;
    if (r < M)
      *(float4*)(C + (size_t)r * N + bn + tn * 4) =
        make_float4(acc[i][0], acc[i][1], acc[i][2], acc[i][3]);
    float ps = acc[i][0]*s.x + acc[i][1]*s.y + acc[i][2]*s.z + acc[i][3]*s.w;
    float pd = acc[i][0]*d.x + acc[i][1]*d.y + acc[i][2]*d.z + acc[i][3]*d.w;
    ps += __shfl_xor(ps, 1); ps += __shfl_xor(ps, 2); ps += __shfl_xor(ps, 4); ps += __shfl_xor(ps, 8);
    pd += __shfl_xor(pd, 1); pd += __shfl_xor(pd, 2); pd += __shfl_xor(pd, 4); pd += __shfl_xor(pd, 8);
    if (tn == 0 && r < M){ atomicAdd(&vs[r], ps); atomicAdd(&vd[r], pd); }
  }
}

// ---------------- fp32 GEMM 64x64 + fused full row-dots (stage 3), BM=64, pipelined ----------------
__global__ __launch_bounds__(256) void k_gemm64_dots(
    const float* __restrict__ A, const float* __restrict__ B, float* __restrict__ C,
    int M, int N, int K, const float* __restrict__ a_s, const float* __restrict__ a_d,
    float* __restrict__ vs, float* __restrict__ vd){
  __shared__ float As[16][68];
  __shared__ float Bs[16][64];
  int tid = threadIdx.x;
  int tn = tid & 15, tm = tid >> 4;
  int bm = blockIdx.x * 64;

  float acc[4][4];
  #pragma unroll
  for (int i = 0; i < 4; i++)
    #pragma unroll
    for (int j = 0; j < 4; j++) acc[i][j] = 0.f;

  int arow = tid >> 2, akc = (tid & 3) * 4;
  int brow = tid >> 4, bcol = (tid & 15) * 4;
  int gr = bm + arow;

  float4 pa, pb;
  pa = (gr < M) ? *(const float4*)(A + (size_t)gr * K + akc) : make_float4(0,0,0,0);
  pb = *(const float4*)(B + (size_t)brow * N + bcol);

  for (int k0 = 0; k0 < K; k0 += 16){
    As[akc + 0][arow] = pa.x; As[akc + 1][arow] = pa.y;
    As[akc + 2][arow] = pa.z; As[akc + 3][arow] = pa.w;
    *(float4*)&Bs[brow][bcol] = pb;
    __syncthreads();

    int k1 = k0 + 16;
    if (k1 < K){
      pa = (gr < M) ? *(const float4*)(A + (size_t)gr * K + k1 + akc) : make_float4(0,0,0,0);
      pb = *(const float4*)(B + (size_t)(k1 + brow) * N + bcol);
    }

    #pragma unroll
    for (int k = 0; k < 16; k++){
      float4 a = *(const float4*)&As[k][tm * 4];
      float4 b = *(const float4*)&Bs[k][tn * 4];
      float av[4] = {a.x, a.y, a.z, a.w};
      float bb[4] = {b.x, b.y, b.z, b.w};
      #pragma unroll
      for (int i = 0; i < 4; i++)
        #pragma unroll
        for (int j = 0; j < 4; j++) acc[i][j] += av[i] * bb[j];
    }
    __syncthreads();
  }
  float4 s = *(const float4*)(a_s + tn * 4);
  float4 d = *(const float4*)(a_d + tn * 4);
  #pragma unroll
  for (int i = 0; i < 4; i++){
    int r = bm + tm * 4 + i;
    if (r < M)
      *(float4*)(C + (size_t)r * N + tn * 4) = make_float4(acc[i][0], acc[i][1], acc[i][2], acc[i][3]);
    float ps = acc[i][0]*s.x + acc[i][1]*s.y + acc[i][2]*s.z + acc[i][3]*s.w;
    float pd = acc[i][0]*d.x + acc[i][1]*d.y + acc[i][2]*d.z + acc[i][3]*d.w;
    ps += __shfl_xor(ps, 1); ps += __shfl_xor(ps, 2); ps += __shfl_xor(ps, 4); ps += __shfl_xor(ps, 8);
    pd += __shfl_xor(pd, 1); pd += __shfl_xor(pd, 2); pd += __shfl_xor(pd, 4); pd += __shfl_xor(pd, 8);
    if (tn == 0 && r < M){ vs[r] = ps; vd[r] = pd; }
  }
}

// ---------------- hypergraph aggregation in 128-dim input space ----------------
__global__ __launch_bounds__(256) void k_hg_edge128(const float* __restrict__ x, const int* __restrict__ off,
                                                    const int* __restrict__ heNodes, float* __restrict__ mout,
                                                    int nhe){
  int wid = (blockIdx.x * blockDim.x + threadIdx.x) >> 6;
  int lane = threadIdx.x & 63;
  if (wid >= nhe) return;
  int s = off[wid], e = off[wid + 1];
  float2 a0 = make_float2(0,0), a1 = a0, a2 = a0, a3 = a0;
  int i = s;
  for (; i + 8 <= e; i += 8){
    int n8[8];
    #pragma unroll
    for (int u = 0; u < 8; u++) n8[u] = heNodes[i + u];
    float2 v8[8];
    #pragma unroll
    for (int u = 0; u < 8; u++) v8[u] = *(const float2*)(x + (size_t)n8[u] * 128 + lane * 2);
    #pragma unroll
    for (int u = 0; u < 8; u++){
      float2* c = (u & 3) == 0 ? &a0 : (u & 3) == 1 ? &a1 : (u & 3) == 2 ? &a2 : &a3;
      c->x += v8[u].x; c->y += v8[u].y;
    }
  }
  for (; i < e; i++){
    int nd = heNodes[i];
    float2 v = *(const float2*)(x + (size_t)nd * 128 + lane * 2);
    a0.x += v.x; a0.y += v.y;
  }
  float inv = (e > s) ? 1.f / (float)(e - s) : 0.f;
  float2 o = make_float2((a0.x + a1.x + a2.x + a3.x) * inv, (a0.y + a1.y + a2.y + a3.y) * inv);
  *(float2*)(mout + (size_t)wid * 128 + lane * 2) = o;
}

__global__ __launch_bounds__(256) void k_hg_node128(const float* __restrict__ m_in, const int* __restrict__ off,
                                                    const int* __restrict__ nHEs, float* __restrict__ out,
                                                    int nn){
  int wid = (blockIdx.x * blockDim.x + threadIdx.x) >> 6;
  int lane = threadIdx.x & 63;
  if (wid >= nn) return;
  int s = off[wid], e = off[wid + 1];
  float2 a0 = make_float2(0,0), a1 = a0, a2 = a0, a3 = a0;
  int i = s;
  for (; i + 4 <= e; i += 4){
    int n0 = nHEs[i], n1 = nHEs[i+1], n2 = nHEs[i+2], n3 = nHEs[i+3];
    float2 v0 = *(const float2*)(m_in + (size_t)n0 * 128 + lane * 2);
    float2 v1 = *(const float2*)(m_in + (size_t)n1 * 128 + lane * 2);
    float2 v2 = *(const float2*)(m_in + (size_t)n2 * 128 + lane * 2);
    float2 v3 = *(const float2*)(m_in + (size_t)n3 * 128 + lane * 2);
    a0.x += v0.x; a0.y += v0.y; a1.x += v1.x; a1.y += v1.y;
    a2.x += v2.x; a2.y += v2.y; a3.x += v3.x; a3.y += v3.y;
  }
  for (; i < e; i++){
    int he = nHEs[i];
    float2 v = *(const float2*)(m_in + (size_t)he * 128 + lane * 2);
    a0.x += v.x; a0.y += v.y;
  }
  float inv = (e > s) ? 1.f / (float)(e - s) : 0.f;
  float2 o = make_float2((a0.x + a1.x + a2.x + a3.x) * inv, (a0.y + a1.y + a2.y + a3.y) * inv);
  *(float2*)(out + (size_t)wid * 128 + lane * 2) = o;
}

// ---------------- GAT aggregation, fused softmax, no max pass, 8x unroll ----------------
__global__ __launch_bounds__(256) void k_gat256(const float* __restrict__ h, const float* __restrict__ asr,
                                                const float* __restrict__ ads, const int* __restrict__ off,
                                                const int* __restrict__ srcIdx, const float* __restrict__ bias,
                                                float* __restrict__ out, int nn){
  int wid = (blockIdx.x * blockDim.x + threadIdx.x) >> 6;
  int lane = threadIdx.x & 63;
  if (wid >= nn) return;
  float ad = ads[wid];
  int s = off[wid], e = off[wid + 1];

  float ssum = 0.f;
  float4 c0 = make_float4(0,0,0,0), c1 = c0, c2 = c0, c3 = c0;
  {
    float e0 = __expf(lrelu(asr[wid] + ad));   // self-loop
    ssum += e0;
    float4 v = *(const float4*)(h + (size_t)wid * 256 + lane * 4);
    c0.x += e0 * v.x; c0.y += e0 * v.y; c0.z += e0 * v.z; c0.w += e0 * v.w;
  }
  int i = s;
  for (; i + 8 <= e; i += 8){
    int n8[8];
    #pragma unroll
    for (int u = 0; u < 8; u++) n8[u] = srcIdx[i + u];
    float f8[8];
    #pragma unroll
    for (int u = 0; u < 8; u++) f8[u] = asr[n8[u]];
    float4 v8[8];
    #pragma unroll
    for (int u = 0; u < 8; u++) v8[u] = *(const float4*)(h + (size_t)n8[u] * 256 + lane * 4);
    #pragma unroll
    for (int u = 0; u < 8; u++){
      float ee = __expf(lrelu(f8[u] + ad));
      ssum += ee;
      float4* c = (u & 3) == 0 ? &c0 : (u & 3) == 1 ? &c1 : (u & 3) == 2 ? &c2 : &c3;
      c->x += ee * v8[u].x; c->y += ee * v8[u].y; c->z += ee * v8[u].z; c->w += ee * v8[u].w;
    }
  }
  for (; i < e; i++){
    int sn = srcIdx[i];
    float ee = __expf(lrelu(asr[sn] + ad));
    ssum += ee;
    float4 v = *(const float4*)(h + (size_t)sn * 256 + lane * 4);
    c0.x += ee * v.x; c0.y += ee * v.y; c0.z += ee * v.z; c0.w += ee * v.w;
  }
  float r = 1.f / (ssum + 1e-16f);
  float4 b = *(const float4*)(bias + lane * 4);
  v4f o;
  o.x = fmaxf((c0.x + c1.x + c2.x + c3.x) * r + b.x, 0.f);
  o.y = fmaxf((c0.y + c1.y + c2.y + c3.y) * r + b.y, 0.f);
  o.z = fmaxf((c0.z + c1.z + c2.z + c3.z) * r + b.z, 0.f);
  o.w = fmaxf((c0.w + c1.w + c2.w + c3.w) * r + b.w, 0.f);
  __builtin_nontemporal_store(o, (v4f*)(out + (size_t)wid * 256 + lane * 4));
}

__global__ __launch_bounds__(256) void k_gat64(const float* __restrict__ h, const float* __restrict__ asr,
                                               const float* __restrict__ ads, const int* __restrict__ off,
                                               const int* __restrict__ srcIdx, const float* __restrict__ bias,
                                               float* __restrict__ out, int nn){
  int wid = (blockIdx.x * blockDim.x + threadIdx.x) >> 6;
  int lane = threadIdx.x & 63;
  if (wid >= nn) return;
  float ad = ads[wid];
  int s = off[wid], e = off[wid + 1];

  float ssum = 0.f;
  float c0 = 0.f, c1 = 0.f, c2 = 0.f, c3 = 0.f;
  {
    float e0 = __expf(lrelu(asr[wid] + ad));
    ssum += e0;
    c0 += e0 * h[(size_t)wid * 64 + lane];
  }
  int i = s;
  for (; i + 8 <= e; i += 8){
    int n8[8];
    #pragma unroll
    for (int u = 0; u < 8; u++) n8[u] = srcIdx[i + u];
    float f8[8], v8[8];
    #pragma unroll
    for (int u = 0; u < 8; u++) f8[u] = asr[n8[u]];
    #pragma unroll
    for (int u = 0; u < 8; u++) v8[u] = h[(size_t)n8[u] * 64 + lane];
    #pragma unroll
    for (int u = 0; u < 8; u++){
      float ee = __expf(lrelu(f8[u] + ad));
      ssum += ee;
      if ((u & 3) == 0) c0 += ee * v8[u];
      else if ((u & 3) == 1) c1 += ee * v8[u];
      else if ((u & 3) == 2) c2 += ee * v8[u];
      else c3 += ee * v8[u];
    }
  }
  for (; i < e; i++){
    int sn = srcIdx[i];
    float ee = __expf(lrelu(asr[sn] + ad));
    ssum += ee;
    c0 += ee * h[(size_t)sn * 64 + lane];
  }
  float r = 1.f / (ssum + 1e-16f);
  out[(size_t)wid * 64 + lane] = fmaxf((c0 + c1 + c2 + c3) * r + bias[lane], 0.f);
}

// ---------------- decode: GEMM-tiled MLP, 64 edges/block (4 blocks/CU), dst prefetch ----------------
#define DEC_EPB 64

__device__ __forceinline__ void dec_stageW(float (*Ws)[68], const float* __restrict__ W, int tid){
  #pragma unroll
  for (int i = 0; i < 4; i++){
    int idx = tid + i * 256;
    int r = idx >> 4, c = (idx & 15) * 4;
    *(float4*)&Ws[r][c] = *(const float4*)(W + r * 64 + c);
  }
}

__device__ __forceinline__ void dec_mac4(const float (*act)[68], const float (*Ws)[68],
                                         int tm, int tn, float (&acc)[4][4]){
  #pragma unroll 8
  for (int k = 0; k < 64; k++){
    float4 a = *(const float4*)&act[k][tm * 4];
    float4 b = *(const float4*)&Ws[k][tn * 4];
    float av[4] = {a.x, a.y, a.z, a.w};
    float bb[4] = {b.x, b.y, b.z, b.w};
    #pragma unroll
    for (int i = 0; i < 4; i++)
      #pragma unroll
      for (int j = 0; j < 4; j++)
        acc[i][j] = fmaf(av[i], bb[j], acc[i][j]);
  }
}

__device__ __forceinline__ void dec_writeback4(float (*act)[68], int tm, int tn, const float (&acc)[4][4]){
  #pragma unroll
  for (int j = 0; j < 4; j++)
    #pragma unroll
    for (int i = 0; i < 4; i++)
      act[tn * 4 + j][tm * 4 + i] = fmaxf(acc[i][j], 0.f);
}

__global__ __launch_bounds__(256) void k_decode(const float* __restrict__ z, const int* __restrict__ eli, int L,
    const float* __restrict__ Wm1, const float* __restrict__ bm1,
    const float* __restrict__ Wm2, const float* __restrict__ bm2,
    const float* __restrict__ Wm3, const float* __restrict__ bm3,
    const float* __restrict__ Wm4, const float* __restrict__ bm4,
    float* __restrict__ outPred, float* __restrict__ outProb, float* __restrict__ outLog){
  __shared__ float act[64][68];   // 17.4 KB
  __shared__ float Ws[64][68];    // 17.4 KB
  __shared__ float W4s[192];
  __shared__ float b1s[64], b2s[64], b3s[64], b4s[4];

  int tid = threadIdx.x, lane = tid & 63, wv = tid >> 6;
  int tm = tid >> 4, tn = tid & 15;
  int ebase = blockIdx.x * DEC_EPB;

  if (tid < 64){ b1s[tid] = bm1[tid]; b2s[tid] = bm2[tid]; b3s[tid] = bm3[tid]; }
  if (tid < 3) b4s[tid] = bm4[tid];
  if (tid < 192) W4s[tid] = Wm4[tid];

  // stage W1 (src half); gather src half to LDS; prefetch dst half into regs
  dec_stageW(Ws, Wm1, tid);
  #pragma unroll
  for (int t = 0; t < 16; t++){
    int le = wv * 16 + t;
    int e = ebase + le;
    int nd = (e < L) ? eli[e] : 0;
    act[lane][le] = z[(size_t)nd * 64 + lane];
  }
  float g[16];
  #pragma unroll
  for (int t = 0; t < 16; t++){
    int e = ebase + wv * 16 + t;
    int nd = (e < L) ? eli[L + e] : 0;
    g[t] = z[(size_t)nd * 64 + lane];
  }
  __syncthreads();

  float acc[4][4];
  {
    float bx = b1s[tn*4], by = b1s[tn*4+1], bz = b1s[tn*4+2], bw = b1s[tn*4+3];
    #pragma unroll
    for (int i = 0; i < 4; i++){ acc[i][0]=bx; acc[i][1]=by; acc[i][2]=bz; acc[i][3]=bw; }
  }
  dec_mac4(act, Ws, tm, tn, acc);   // layer 1, src half (dst gather in flight)
  __syncthreads();

  // write dst half; stage W1 (dst half)
  #pragma unroll
  for (int t = 0; t < 16; t++) act[lane][wv * 16 + t] = g[t];
  dec_stageW(Ws, Wm1 + 4096, tid);
  __syncthreads();
  dec_mac4(act, Ws, tm, tn, acc);   // layer 1, dst half
  __syncthreads();

  dec_writeback4(act, tm, tn, acc);
  dec_stageW(Ws, Wm2, tid);
  __syncthreads();

  {
    float bx = b2s[tn*4], by = b2s[tn*4+1], bz = b2s[tn*4+2], bw = b2s[tn*4+3];
    #pragma unroll
    for (int i = 0; i < 4; i++){ acc[i][0]=bx; acc[i][1]=by; acc[i][2]=bz; acc[i][3]=bw; }
  }
  dec_mac4(act, Ws, tm, tn, acc);   // layer 2
  __syncthreads();
  dec_writeback4(act, tm, tn, acc);
  dec_stageW(Ws, Wm3, tid);
  __syncthreads();

  {
    float bx = b3s[tn*4], by = b3s[tn*4+1], bz = b3s[tn*4+2], bw = b3s[tn*4+3];
    #pragma unroll
    for (int i = 0; i < 4; i++){ acc[i][0]=bx; acc[i][1]=by; acc[i][2]=bz; acc[i][3]=bw; }
  }
  dec_mac4(act, Ws, tm, tn, acc);   // layer 3
  __syncthreads();
  dec_writeback4(act, tm, tn, acc);
  __syncthreads();

  // layer 4 (64->3) + argmax: one edge per thread, first 64 threads
  if (tid < DEC_EPB){
    int e = tid;
    float o0 = b4s[0], o1 = b4s[1], o2 = b4s[2];
    #pragma unroll 8
    for (int k = 0; k < 64; k++){
      float av = act[k][e];
      o0 = fmaf(av, W4s[k*3+0], o0);
      o1 = fmaf(av, W4s[k*3+1], o1);
      o2 = fmaf(av, W4s[k*3+2], o2);
    }
    int eg = ebase + e;
    if (eg < L){
      int am = 0; float best = o0;
      if (o1 > best){ am = 1; best = o1; }
      if (o2 > best){ am = 2; best = o2; }
      outPred[eg] = (float)am;
      outProb[eg] = best;
      outLog[(size_t)eg * 3 + 0] = o0;
      outLog[(size_t)eg * 3 + 1] = o1;
      outLog[(size_t)eg * 3 + 2] = o2;
    }
  }
}

// ---------------- launch ----------------
extern "C" void kernel_launch(void* const* d_in, const int* in_sizes, int n_in,
                              void* d_out, int out_size, void* d_ws, size_t ws_size,
                              hipStream_t stream){
  const float* x      = (const float*)d_in[0];
  const int*   ei     = (const int*)d_in[1];
  const int*   he_node= (const int*)d_in[2];
  const int*   he_edge= (const int*)d_in[3];
  const int*   eli    = (const int*)d_in[4];
  const float* W1  = (const float*)d_in[5];
  const float* b1  = (const float*)d_in[6];
  const float* W2  = (const float*)d_in[7];
  const float* a2s = (const float*)d_in[8];
  const float* a2d = (const float*)d_in[9];
  const float* b2  = (const float*)d_in[10];
  const float* W3  = (const float*)d_in[11];
  const float* a3s = (const float*)d_in[12];
  const float* a3d = (const float*)d_in[13];
  const float* b3  = (const float*)d_in[14];
  const float* Wm1 = (const float*)d_in[15]; const float* bm1 = (const float*)d_in[16];
  const float* Wm2 = (const float*)d_in[17]; const float* bm2 = (const float*)d_in[18];
  const float* Wm3 = (const float*)d_in[19]; const float* bm3 = (const float*)d_in[20];
  const float* Wm4 = (const float*)d_in[21]; const float* bm4 = (const float*)d_in[22];

  const int N   = in_sizes[0] / 128;   // 50000
  const int E   = in_sizes[1] / 2;     // 800000
  const int INC = in_sizes[2];         // 400000
  const int NHE = NHE_CONST;           // 20000
  const int L   = in_sizes[4] / 2;     // 100000

  char* wbase = (char*)d_ws;
  size_t woff = 0;
  auto walloc = [&](size_t bytes) -> void* {
    void* p = wbase + woff;
    woff = (woff + bytes + 255) & ~(size_t)255;
    return p;
  };
  float* pre1   = (float*)walloc((size_t)N * 128 * 4);
  float* mbuf   = (float*)walloc((size_t)NHE * 128 * 4);
  float* h1     = (float*)walloc((size_t)N * 256 * 4);   // also reused as h2
  float* t2     = (float*)walloc((size_t)N * 256 * 4);
  float* t3     = (float*)walloc((size_t)N * 64 * 4);
  float* zbuf   = (float*)walloc((size_t)N * 64 * 4);
  float* vboth  = (float*)walloc((size_t)2 * N * 4);
  int* heOff  = (int*)walloc((size_t)(NHE + 1) * 4);
  int* nOff   = (int*)walloc((size_t)(N + 1) * 4);
  int* dOff   = (int*)walloc((size_t)(N + 1) * 4);
  int* cntAll = (int*)walloc((size_t)(NHE + 2 * N) * 4);
  int* curAll = (int*)walloc((size_t)(NHE + 2 * N) * 4);
  int* heNodes= (int*)walloc((size_t)INC * 4);
  int* nHEs   = (int*)walloc((size_t)INC * 4);
  int* srcIdx = (int*)walloc((size_t)E * 4);
  int* bsumA  = (int*)walloc(64 * 4);
  int* bsumB  = (int*)walloc(64 * 4);
  int* bsumC  = (int*)walloc(64 * 4);

  int* cntHE = cntAll;           int* cntN = cntAll + NHE; int* cntD = cntAll + NHE + N;
  int* curHE = curAll;           int* curN = curAll + NHE; int* curD = curAll + NHE + N;
  float* vsrc = vboth;           float* vdst = vboth + N;
  float* h2 = h1;                // h1 dead after stage-2 GEMM reads it

  const int* srcPtr = ei;
  const int* dstPtr = ei + E;

  // --- CSR build ---
  hipMemsetAsync(cntAll, 0, (size_t)(NHE + 2 * N) * 4, stream);
  hipMemsetAsync(vboth,  0, (size_t)2 * N * 4, stream);
  k_count_all<<<(E + 255) / 256, 256, 0, stream>>>(he_node, he_edge, INC, dstPtr, E, cntN, cntHE, cntD);

  int nbHE = (NHE + 1023) / 1024;
  int nbN  = (N + 1023) / 1024;
  k_scan_sums3<<<dim3(nbN, 3), 256, 0, stream>>>(cntHE, NHE, bsumA, cntN, N, bsumB, cntD, N, bsumC);
  k_scan_bsum3<<<1, 64, 0, stream>>>(bsumA, nbHE, bsumB, nbN, bsumC, nbN);
  k_scan_apply3<<<dim3(nbN, 3), 256, 0, stream>>>(cntHE, NHE, bsumA, heOff, curHE,
                                                  cntN,  N,   bsumB, nOff,  curN,
                                                  cntD,  N,   bsumC, dOff,  curD);
  k_fill_sliced<<<8 * 128, 256, 0, stream>>>(he_node, he_edge, INC, srcPtr, dstPtr, E,
                                             curN, curHE, curD, nHEs, heNodes, srcIdx, N, NHE);

  int gRowA = (N + 127) / 128;
  int gRowB = (N + 63) / 64;
  int gWav  = (N + 3) / 4;

  // --- stage 1: HypergraphConv (aggregate in 128-dim, GEMM last, fused bias+relu) ---
  k_hg_edge128<<<(NHE + 3) / 4, 256, 0, stream>>>(x, heOff, heNodes, mbuf, NHE);
  k_hg_node128<<<gWav, 256, 0, stream>>>(mbuf, nOff, nHEs, pre1, N);
  k_gemm_b64_bias<<<dim3(gRowA, 4), 256, 0, stream>>>(pre1, W1, h1, N, 256, 128, b1);

  // --- stage 2: GAT 256->256 (dots fused into GEMM) ---
  k_gemm_b64_dots<<<dim3(gRowA, 4), 256, 0, stream>>>(h1, W2, t2, N, 256, 256, a2s, a2d, vsrc, vdst);
  k_gat256<<<gWav, 256, 0, stream>>>(t2, vsrc, vdst, dOff, srcIdx, b2, h2, N);

  // --- stage 3: GAT 256->64 (dots fused into GEMM) ---
  k_gemm64_dots<<<gRowB, 256, 0, stream>>>(h2, W3, t3, N, 64, 256, a3s, a3d, vsrc, vdst);
  k_gat64<<<gWav, 256, 0, stream>>>(t3, vsrc, vdst, dOff, srcIdx, b3, zbuf, N);

  // --- decode ---
  float* outPred = (float*)d_out;
  float* outProb = outPred + L;
  float* outLog  = outProb + L;
  k_decode<<<(L + DEC_EPB - 1) / DEC_EPB, 256, 0, stream>>>(zbuf, eli, L,
                                    Wm1, bm1, Wm2, bm2, Wm3, bm3, Wm4, bm4,
                                    outPred, outProb, outLog);
}